// Round 1
// baseline (982.955 us; speedup 1.0000x reference)
//
#include <hip/hip_runtime.h>
#include <math.h>

// LinearAttention: B=2, S=4096, D=1024, H=16, Dh=64
// Pipeline:
//   1) k_qkv     : Q=elu1(X Wq^T), K=elu1(X Wk^T), V=X Wv^T      (fused 3x GEMM-NT)
//   2) k_chunksums: per (b,h,chunk) CKV[d][e]=sum k_i[d] v_i[e], CKS[d]=sum k_i[d]
//   3) k_prefix_* : exclusive prefix over chunks (state before chunk c)
//   4) k_attn    : out = (causal(QK^T)V + Q@state) / (q.ksum + eps)  -> overwrites Q buffer
//   5) k_out     : final GEMM-NT with Wo
// All fp32 (CDNA4 has no fp32 MFMA; round 1 = correctness + baseline).

#define EPSF 1e-8f

__device__ __forceinline__ float elu1(float x) { return x > 0.f ? x + 1.f : __expf(x); }
__device__ __forceinline__ void f4a(float4 v, float* a) { a[0]=v.x; a[1]=v.y; a[2]=v.z; a[3]=v.w; }

// ---------------- Kernel 1: fused QKV projection GEMM (NT) ----------------
// grid (128, 16), block 256.  Tiles: BM=64, BN=64, BK=16, 4x4 micro-tile/thread.
__global__ __launch_bounds__(256) void k_qkv(
    const float* __restrict__ X,  const float* __restrict__ Wq,
    const float* __restrict__ Wk, const float* __restrict__ Wv,
    float* __restrict__ Q, float* __restrict__ K, float* __restrict__ V)
{
    const int tid = threadIdx.x;
    const int tx = tid & 15, ty = tid >> 4;
    const int m0 = blockIdx.x * 64;
    const int n0 = blockIdx.y * 64;
    const int lr = tid >> 2;            // 0..63  (tile row)
    const int lk = (tid & 3) << 2;      // 0,4,8,12 (k offset)

    __shared__ float Xs[16][64];        // transposed: Xs[k][m]
    __shared__ float Ws[3][16][64];     // transposed: Ws[q][k][n]

    float acc[3][4][4] = {};

    for (int kt = 0; kt < 1024; kt += 16) {
        float4 xv = *(const float4*)&X [(size_t)(m0 + lr) * 1024 + kt + lk];
        float4 w0 = *(const float4*)&Wq[(size_t)(n0 + lr) * 1024 + kt + lk];
        float4 w1 = *(const float4*)&Wk[(size_t)(n0 + lr) * 1024 + kt + lk];
        float4 w2 = *(const float4*)&Wv[(size_t)(n0 + lr) * 1024 + kt + lk];
        __syncthreads();
        Xs[lk+0][lr]=xv.x; Xs[lk+1][lr]=xv.y; Xs[lk+2][lr]=xv.z; Xs[lk+3][lr]=xv.w;
        Ws[0][lk+0][lr]=w0.x; Ws[0][lk+1][lr]=w0.y; Ws[0][lk+2][lr]=w0.z; Ws[0][lk+3][lr]=w0.w;
        Ws[1][lk+0][lr]=w1.x; Ws[1][lk+1][lr]=w1.y; Ws[1][lk+2][lr]=w1.z; Ws[1][lk+3][lr]=w1.w;
        Ws[2][lk+0][lr]=w2.x; Ws[2][lk+1][lr]=w2.y; Ws[2][lk+2][lr]=w2.z; Ws[2][lk+3][lr]=w2.w;
        __syncthreads();
        #pragma unroll
        for (int kk = 0; kk < 16; ++kk) {
            float av[4], b0[4], b1[4], b2[4];
            f4a(*(const float4*)&Xs[kk][ty*4],    av);
            f4a(*(const float4*)&Ws[0][kk][tx*4], b0);
            f4a(*(const float4*)&Ws[1][kk][tx*4], b1);
            f4a(*(const float4*)&Ws[2][kk][tx*4], b2);
            #pragma unroll
            for (int ii = 0; ii < 4; ++ii)
                #pragma unroll
                for (int jj = 0; jj < 4; ++jj) {
                    acc[0][ii][jj] = fmaf(av[ii], b0[jj], acc[0][ii][jj]);
                    acc[1][ii][jj] = fmaf(av[ii], b1[jj], acc[1][ii][jj]);
                    acc[2][ii][jj] = fmaf(av[ii], b2[jj], acc[2][ii][jj]);
                }
        }
    }
    #pragma unroll
    for (int ii = 0; ii < 4; ++ii) {
        size_t r = (size_t)(m0 + ty*4 + ii) * 1024 + n0 + tx*4;
        float4 q4 = make_float4(elu1(acc[0][ii][0]), elu1(acc[0][ii][1]),
                                elu1(acc[0][ii][2]), elu1(acc[0][ii][3]));
        float4 k4 = make_float4(elu1(acc[1][ii][0]), elu1(acc[1][ii][1]),
                                elu1(acc[1][ii][2]), elu1(acc[1][ii][3]));
        float4 v4 = make_float4(acc[2][ii][0], acc[2][ii][1], acc[2][ii][2], acc[2][ii][3]);
        *(float4*)&Q[r] = q4;
        *(float4*)&K[r] = k4;
        *(float4*)&V[r] = v4;
    }
}

// ---------------- Kernel 2a: per-chunk KV sums ----------------
// grid 2048 (= B*H*NC, blockIdx = bh*64 + c), block 256.
__global__ __launch_bounds__(256) void k_chunksums(
    const float* __restrict__ Kg, const float* __restrict__ Vg,
    float* __restrict__ CKV, float* __restrict__ CKS)
{
    const int tid = threadIdx.x;
    const int tx = tid & 15, ty = tid >> 4;
    const int c  = blockIdx.x & 63;
    const int bh = blockIdx.x >> 6;
    const int b = bh >> 4, h = bh & 15;
    const int row0 = b * 4096 + c * 64;
    const int col  = h * 64;

    __shared__ float Ks[64][68];
    __shared__ float Vs[64][68];

    #pragma unroll
    for (int r = 0; r < 4; ++r) {
        int idx = tid + r * 256;           // 0..1023
        int i = idx >> 4, cg = (idx & 15) << 2;
        *(float4*)&Ks[i][cg] = *(const float4*)&Kg[(size_t)(row0 + i) * 1024 + col + cg];
        *(float4*)&Vs[i][cg] = *(const float4*)&Vg[(size_t)(row0 + i) * 1024 + col + cg];
    }
    __syncthreads();

    float acc[4][4] = {};
    #pragma unroll 8
    for (int i = 0; i < 64; ++i) {
        float kv[4], vv[4];
        f4a(*(const float4*)&Ks[i][ty*4], kv);
        f4a(*(const float4*)&Vs[i][tx*4], vv);
        #pragma unroll
        for (int a = 0; a < 4; ++a)
            #pragma unroll
            for (int e = 0; e < 4; ++e)
                acc[a][e] = fmaf(kv[a], vv[e], acc[a][e]);
    }
    float* ckv = &CKV[(size_t)blockIdx.x * 4096];
    #pragma unroll
    for (int a = 0; a < 4; ++a)
        *(float4*)&ckv[(ty*4 + a) * 64 + tx*4] =
            make_float4(acc[a][0], acc[a][1], acc[a][2], acc[a][3]);

    if (tid < 64) {
        float s = 0.f;
        #pragma unroll 8
        for (int i = 0; i < 64; ++i) s += Ks[i][tid];
        CKS[(size_t)blockIdx.x * 64 + tid] = s;
    }
}

// ---------------- Kernel 2b: exclusive prefix over chunks ----------------
// CKV: grid 512 (bh*16 + slice), block 256; each thread owns one of 4096 positions.
__global__ __launch_bounds__(256) void k_prefix_kv(float* __restrict__ CKV)
{
    const int bh = blockIdx.x >> 4;
    const int p  = ((blockIdx.x & 15) << 8) + threadIdx.x;   // 0..4095
    const size_t base = (size_t)bh * 64 * 4096 + p;
    float v[64];
    #pragma unroll
    for (int c = 0; c < 64; ++c) v[c] = CKV[base + (size_t)c * 4096];
    float acc = 0.f;
    #pragma unroll
    for (int c = 0; c < 64; ++c) { float t = v[c]; CKV[base + (size_t)c * 4096] = acc; acc += t; }
}

// CKS: grid 8, block 256; thread = (bh, d)
__global__ __launch_bounds__(256) void k_prefix_ks(float* __restrict__ CKS)
{
    const int idx = blockIdx.x * 256 + threadIdx.x;  // 0..2047
    const int bh = idx >> 6, d = idx & 63;
    const size_t base = (size_t)bh * 64 * 64 + d;
    float v[64];
    #pragma unroll
    for (int c = 0; c < 64; ++c) v[c] = CKS[base + (size_t)c * 64];
    float acc = 0.f;
    #pragma unroll
    for (int c = 0; c < 64; ++c) { float t = v[c]; CKS[base + (size_t)c * 64] = acc; acc += t; }
}

// ---------------- Kernel 2c: per-chunk attention output ----------------
// grid 2048 (bh*64 + c), block 256. Writes AO in-place over Q (same rows/cols only).
__global__ __launch_bounds__(256) void k_attn(
    const float* __restrict__ Qg, const float* __restrict__ Kg, const float* __restrict__ Vg,
    const float* __restrict__ CKV, const float* __restrict__ CKS, float* __restrict__ AO)
{
    const int tid = threadIdx.x;
    const int tx = tid & 15, ty = tid >> 4;
    const int c  = blockIdx.x & 63;
    const int bh = blockIdx.x >> 6;
    const int b = bh >> 4, h = bh & 15;
    const int row0 = b * 4096 + c * 64;
    const int col  = h * 64;

    __shared__ float Qs[64][68];
    __shared__ float KVs[64][68];     // first K, then V
    __shared__ float AsT[64][64];     // A transposed: AsT[j][i]
    __shared__ float ksumP[64];
    __shared__ float invden[64];

    #pragma unroll
    for (int r = 0; r < 4; ++r) {
        int idx = tid + r * 256;
        int i = idx >> 4, cg = (idx & 15) << 2;
        *(float4*)&Qs[i][cg]  = *(const float4*)&Qg[(size_t)(row0 + i) * 1024 + col + cg];
        *(float4*)&KVs[i][cg] = *(const float4*)&Kg[(size_t)(row0 + i) * 1024 + col + cg];
    }
    if (tid < 64) ksumP[tid] = CKS[(size_t)blockIdx.x * 64 + tid];
    __syncthreads();

    // A[i][j] = q_i . k_j  (masked j<=i), stored transposed
    float a[4][4] = {};
    #pragma unroll 4
    for (int d = 0; d < 64; d += 4) {
        float qv[4][4], kv[4][4];
        #pragma unroll
        for (int ii = 0; ii < 4; ++ii) f4a(*(const float4*)&Qs[ty*4 + ii][d], qv[ii]);
        #pragma unroll
        for (int jj = 0; jj < 4; ++jj) f4a(*(const float4*)&KVs[tx*4 + jj][d], kv[jj]);
        #pragma unroll
        for (int ii = 0; ii < 4; ++ii)
            #pragma unroll
            for (int jj = 0; jj < 4; ++jj)
                #pragma unroll
                for (int dd = 0; dd < 4; ++dd)
                    a[ii][jj] = fmaf(qv[ii][dd], kv[jj][dd], a[ii][jj]);
    }
    #pragma unroll
    for (int ii = 0; ii < 4; ++ii)
        #pragma unroll
        for (int jj = 0; jj < 4; ++jj) {
            int i = ty*4 + ii, j = tx*4 + jj;
            AsT[j][i] = (j <= i) ? a[ii][jj] : 0.f;
        }
    __syncthreads();

    // load V over K (safe: K reads done), while threads<64 compute denominators
    #pragma unroll
    for (int r = 0; r < 4; ++r) {
        int idx = tid + r * 256;
        int i = idx >> 4, cg = (idx & 15) << 2;
        *(float4*)&KVs[i][cg] = *(const float4*)&Vg[(size_t)(row0 + i) * 1024 + col + cg];
    }
    if (tid < 64) {
        float s = EPSF;
        #pragma unroll 8
        for (int d = 0; d < 64; ++d) s += Qs[tid][d] * ksumP[d];
        #pragma unroll 8
        for (int j = 0; j < 64; ++j) s += AsT[j][tid];   // masked entries are 0
        invden[tid] = 1.f / s;
    }
    __syncthreads();

    // out[i][e] = sum_j A[i][j] V[j][e] + sum_d Q[i][d] St[d][e]
    float o[4][4] = {};
    #pragma unroll 8
    for (int j = 0; j < 64; ++j) {
        float av[4], vv[4];
        f4a(*(const float4*)&AsT[j][ty*4], av);
        f4a(*(const float4*)&KVs[j][tx*4], vv);
        #pragma unroll
        for (int ii = 0; ii < 4; ++ii)
            #pragma unroll
            for (int jj = 0; jj < 4; ++jj)
                o[ii][jj] = fmaf(av[ii], vv[jj], o[ii][jj]);
    }
    const float* St = &CKV[(size_t)blockIdx.x * 4096];
    #pragma unroll 4
    for (int d = 0; d < 64; ++d) {
        float sv[4];
        f4a(*(const float4*)&St[d * 64 + tx*4], sv);
        float qd[4];
        #pragma unroll
        for (int ii = 0; ii < 4; ++ii) qd[ii] = Qs[ty*4 + ii][d];
        #pragma unroll
        for (int ii = 0; ii < 4; ++ii)
            #pragma unroll
            for (int jj = 0; jj < 4; ++jj)
                o[ii][jj] = fmaf(qd[ii], sv[jj], o[ii][jj]);
    }
    #pragma unroll
    for (int ii = 0; ii < 4; ++ii) {
        int i = ty*4 + ii;
        float id = invden[i];
        *(float4*)&AO[(size_t)(row0 + i) * 1024 + col + tx*4] =
            make_float4(o[ii][0]*id, o[ii][1]*id, o[ii][2]*id, o[ii][3]*id);
    }
}

// ---------------- Kernel 3: final output GEMM (NT), no activation ----------------
__global__ __launch_bounds__(256) void k_out(
    const float* __restrict__ A, const float* __restrict__ W, float* __restrict__ O)
{
    const int tid = threadIdx.x;
    const int tx = tid & 15, ty = tid >> 4;
    const int m0 = blockIdx.x * 64;
    const int n0 = blockIdx.y * 64;
    const int lr = tid >> 2;
    const int lk = (tid & 3) << 2;

    __shared__ float As[16][64];
    __shared__ float Ws[16][64];

    float acc[4][4] = {};
    for (int kt = 0; kt < 1024; kt += 16) {
        float4 av = *(const float4*)&A[(size_t)(m0 + lr) * 1024 + kt + lk];
        float4 wv = *(const float4*)&W[(size_t)(n0 + lr) * 1024 + kt + lk];
        __syncthreads();
        As[lk+0][lr]=av.x; As[lk+1][lr]=av.y; As[lk+2][lr]=av.z; As[lk+3][lr]=av.w;
        Ws[lk+0][lr]=wv.x; Ws[lk+1][lr]=wv.y; Ws[lk+2][lr]=wv.z; Ws[lk+3][lr]=wv.w;
        __syncthreads();
        #pragma unroll
        for (int kk = 0; kk < 16; ++kk) {
            float a4[4], b4[4];
            f4a(*(const float4*)&As[kk][ty*4], a4);
            f4a(*(const float4*)&Ws[kk][tx*4], b4);
            #pragma unroll
            for (int ii = 0; ii < 4; ++ii)
                #pragma unroll
                for (int jj = 0; jj < 4; ++jj)
                    acc[ii][jj] = fmaf(a4[ii], b4[jj], acc[ii][jj]);
        }
    }
    #pragma unroll
    for (int ii = 0; ii < 4; ++ii) {
        size_t r = (size_t)(m0 + ty*4 + ii) * 1024 + n0 + tx*4;
        *(float4*)&O[r] = make_float4(acc[ii][0], acc[ii][1], acc[ii][2], acc[ii][3]);
    }
}

extern "C" void kernel_launch(void* const* d_in, const int* in_sizes, int n_in,
                              void* d_out, int out_size, void* d_ws, size_t ws_size,
                              hipStream_t stream)
{
    const float* x  = (const float*)d_in[0];
    const float* Wq = (const float*)d_in[1];
    const float* Wk = (const float*)d_in[2];
    const float* Wv = (const float*)d_in[3];
    const float* Wo = (const float*)d_in[4];
    float* out = (float*)d_out;

    float* ws = (float*)d_ws;
    const size_t NM = (size_t)8192 * 1024;       // 8.39M floats
    float* Q   = ws;              // later re-used as attention output
    float* K   = ws + NM;
    float* V   = ws + 2 * NM;
    float* CKV = ws + 3 * NM;     // B*H*NC*64*64 = 8.39M floats
    float* CKS = ws + 4 * NM;     // B*H*NC*64    = 131072 floats

    k_qkv      <<<dim3(128, 16), 256, 0, stream>>>(x, Wq, Wk, Wv, Q, K, V);
    k_chunksums<<<2048,          256, 0, stream>>>(K, V, CKV, CKS);
    k_prefix_kv<<<512,           256, 0, stream>>>(CKV);
    k_prefix_ks<<<8,             256, 0, stream>>>(CKS);
    k_attn     <<<2048,          256, 0, stream>>>(Q, K, V, CKV, CKS, Q);
    k_out      <<<dim3(128, 16), 256, 0, stream>>>(Q, Wo, out);
}

// Round 2
// 214.853 us; speedup vs baseline: 4.5750x; 4.5750x over previous
//
#include <hip/hip_runtime.h>
#include <math.h>

// LinearAttention: B=2, S=4096, D=1024, H=16, Dh=64
// Round 2: all GEMMs -> bf16 MFMA (m97 structure); attention chunk kernels fp32
// internal math with bf16 I/O. Pipeline:
//   1) k_cast5     : x, Wq, Wk, Wv, Wo  -> bf16
//   2) k_gemm_nt<1>: Qb = bf16(elu1(x Wq^T)), Kb likewise   (MFMA)
//      k_gemm_nt<2>: Vb = bf16(x Wv^T)                      (MFMA)
//   3) k_chunksums : per (b,h,chunk) CKV/CKS sums (fp32)
//   4) k_prefix_*  : exclusive prefix over chunks
//   5) k_attn      : out = (causal(QK^T)V + Q@state)/den -> bf16 AOb (aliases xb)
//   6) k_gemm_nt<3>: d_out = AOb Wo^T (fp32 out)            (MFMA)

#define EPSF 1e-8f

typedef unsigned short u16;
typedef unsigned int   u32;
typedef __attribute__((ext_vector_type(8))) short short8v;
typedef __attribute__((ext_vector_type(4))) float f32x4;

__device__ __forceinline__ float elu1(float x){ return x > 0.f ? x + 1.f : __expf(x); }
__device__ __forceinline__ u16 f2bf(float f){
    union{float f; u32 i;} c; c.f = f;
    u32 i = c.i + 0x7FFFu + ((c.i >> 16) & 1u);   // RNE
    return (u16)(i >> 16);
}
__device__ __forceinline__ float bflo(u32 v){ union{u32 i; float f;} c; c.i = v << 16; return c.f; }
__device__ __forceinline__ float bfhi(u32 v){ union{u32 i; float f;} c; c.i = v & 0xffff0000u; return c.f; }
__device__ __forceinline__ void f4a(float4 v, float* a){ a[0]=v.x; a[1]=v.y; a[2]=v.z; a[3]=v.w; }

__device__ __forceinline__ void gload16(const void* g, void* l){
    __builtin_amdgcn_global_load_lds((const __attribute__((address_space(1))) u32*)g,
                                     (__attribute__((address_space(3))) u32*)l, 16, 0, 0);
}

// ---------------- Kernel 0: cast fp32 -> bf16 (x + 4 weights) ----------------
// All segment sizes are multiples of 2048 -> each block stays in one segment.
__global__ __launch_bounds__(256) void k_cast5(
    const float* __restrict__ x,  const float* __restrict__ wq,
    const float* __restrict__ wk, const float* __restrict__ wv,
    const float* __restrict__ wo,
    u16* __restrict__ xb, u16* __restrict__ wqb, u16* __restrict__ wkb,
    u16* __restrict__ wvb, u16* __restrict__ wob)
{
    size_t i8 = ((size_t)blockIdx.x * 256 + threadIdx.x) * 8;
    const float* s; u16* d; size_t off;
    if      (i8 <  8388608) { s = x;  d = xb;  off = i8; }
    else if (i8 <  9437184) { s = wq; d = wqb; off = i8 - 8388608; }
    else if (i8 < 10485760) { s = wk; d = wkb; off = i8 - 9437184; }
    else if (i8 < 11534336) { s = wv; d = wvb; off = i8 - 10485760; }
    else                    { s = wo; d = wob; off = i8 - 11534336; }
    float4 a = *(const float4*)&s[off];
    float4 b = *(const float4*)&s[off + 4];
    uint4 p;
    p.x = (u32)f2bf(a.x) | ((u32)f2bf(a.y) << 16);
    p.y = (u32)f2bf(a.z) | ((u32)f2bf(a.w) << 16);
    p.z = (u32)f2bf(b.x) | ((u32)f2bf(b.y) << 16);
    p.w = (u32)f2bf(b.z) | ((u32)f2bf(b.w) << 16);
    *(uint4*)&d[off] = p;
}

// ---------------- MFMA GEMM-NT (m97 structure) ----------------
// C[M][1024] = A[M][1024] * Bm[1024][1024]^T ; A,Bm bf16 ; 128x128 tile, BK=32.
// MODE 1: bf16 out + elu1 ; MODE 2: bf16 out ; MODE 3: f32 out.
template<int MODE>
__global__ __launch_bounds__(256) void k_gemm_nt(
    const u16* __restrict__ A, const u16* __restrict__ Bm, void* __restrict__ C)
{
    __shared__ __align__(16) u16 As[128 * 32];
    __shared__ __align__(16) u16 Bs[128 * 32];
    const int tid = threadIdx.x;
    const int l   = tid & 63;
    const int wv  = tid >> 6;           // wave 0..3
    const int wr  = (wv >> 1) * 64;     // wave's row quadrant
    const int wc  = (wv & 1) * 64;      // wave's col quadrant
    const int m0  = blockIdx.x * 128;
    const int n0  = blockIdx.y * 128;
    const int srow  = tid >> 2;         // staging row 0..63
    const int skoff = (tid & 3) * 8;    // staging k-offset (elements)

    f32x4 acc[4][4];
    #pragma unroll
    for (int m = 0; m < 4; ++m)
        #pragma unroll
        for (int n = 0; n < 4; ++n) acc[m][n] = (f32x4){0.f, 0.f, 0.f, 0.f};

    for (int kt = 0; kt < 1024; kt += 32) {
        __syncthreads();   // previous compute done reading LDS
        #pragma unroll
        for (int h = 0; h < 2; ++h)
            gload16(&A[(size_t)(m0 + h*64 + srow) * 1024 + kt + skoff],
                    (char*)As + h*4096 + wv*1024);
        #pragma unroll
        for (int h = 0; h < 2; ++h)
            gload16(&Bm[(size_t)(n0 + h*64 + srow) * 1024 + kt + skoff],
                    (char*)Bs + h*4096 + wv*1024);
        __syncthreads();   // drains vmcnt -> LDS tiles ready

        short8v a[4], b[4];
        #pragma unroll
        for (int m = 0; m < 4; ++m)
            a[m] = *(const short8v*)&As[(wr + m*16 + (l & 15)) * 32 + (l >> 4) * 8];
        #pragma unroll
        for (int n = 0; n < 4; ++n)
            b[n] = *(const short8v*)&Bs[(wc + n*16 + (l & 15)) * 32 + (l >> 4) * 8];
        #pragma unroll
        for (int m = 0; m < 4; ++m)
            #pragma unroll
            for (int n = 0; n < 4; ++n)
                acc[m][n] = __builtin_amdgcn_mfma_f32_16x16x32_bf16(a[m], b[n], acc[m][n], 0, 0, 0);
    }

    // C/D layout: col = lane&15, row = (lane>>4)*4 + reg   [m89/m91 verified]
    const int r0 = m0 + wr + (l >> 4) * 4;
    const int c0 = n0 + wc + (l & 15);
    #pragma unroll
    for (int m = 0; m < 4; ++m)
        #pragma unroll
        for (int n = 0; n < 4; ++n)
            #pragma unroll
            for (int r = 0; r < 4; ++r) {
                float v = acc[m][n][r];
                if (MODE == 1) v = elu1(v);
                size_t idx = (size_t)(r0 + m*16 + r) * 1024 + c0 + n*16;
                if (MODE == 3) ((float*)C)[idx] = v;
                else           ((u16*)C)[idx]  = f2bf(v);
            }
}

// ---------------- per-chunk KV sums (bf16 in, fp32 out) ----------------
// grid 2048 (= B*H*NC, blockIdx = bh*64 + c), block 256.
__global__ __launch_bounds__(256) void k_chunksums(
    const u16* __restrict__ Kg, const u16* __restrict__ Vg,
    float* __restrict__ CKV, float* __restrict__ CKS)
{
    const int tid = threadIdx.x;
    const int tx = tid & 15, ty = tid >> 4;
    const int c  = blockIdx.x & 63;
    const int bh = blockIdx.x >> 6;
    const int b = bh >> 4, h = bh & 15;
    const int row0 = b * 4096 + c * 64;
    const int col  = h * 64;

    __shared__ float Ks[64][68];
    __shared__ float Vs[64][68];

    #pragma unroll
    for (int r = 0; r < 2; ++r) {
        int idx = tid + r * 256;            // 0..511, each loads 8 bf16
        int i = idx >> 3, cg = (idx & 7) << 3;
        uint4 ku = *(const uint4*)&Kg[(size_t)(row0 + i) * 1024 + col + cg];
        uint4 vu = *(const uint4*)&Vg[(size_t)(row0 + i) * 1024 + col + cg];
        Ks[i][cg+0]=bflo(ku.x); Ks[i][cg+1]=bfhi(ku.x);
        Ks[i][cg+2]=bflo(ku.y); Ks[i][cg+3]=bfhi(ku.y);
        Ks[i][cg+4]=bflo(ku.z); Ks[i][cg+5]=bfhi(ku.z);
        Ks[i][cg+6]=bflo(ku.w); Ks[i][cg+7]=bfhi(ku.w);
        Vs[i][cg+0]=bflo(vu.x); Vs[i][cg+1]=bfhi(vu.x);
        Vs[i][cg+2]=bflo(vu.y); Vs[i][cg+3]=bfhi(vu.y);
        Vs[i][cg+4]=bflo(vu.z); Vs[i][cg+5]=bfhi(vu.z);
        Vs[i][cg+6]=bflo(vu.w); Vs[i][cg+7]=bfhi(vu.w);
    }
    __syncthreads();

    float acc[4][4] = {};
    #pragma unroll 8
    for (int i = 0; i < 64; ++i) {
        float kv[4], vv[4];
        f4a(*(const float4*)&Ks[i][ty*4], kv);
        f4a(*(const float4*)&Vs[i][tx*4], vv);
        #pragma unroll
        for (int a = 0; a < 4; ++a)
            #pragma unroll
            for (int e = 0; e < 4; ++e)
                acc[a][e] = fmaf(kv[a], vv[e], acc[a][e]);
    }
    float* ckv = &CKV[(size_t)blockIdx.x * 4096];
    #pragma unroll
    for (int a = 0; a < 4; ++a)
        *(float4*)&ckv[(ty*4 + a) * 64 + tx*4] =
            make_float4(acc[a][0], acc[a][1], acc[a][2], acc[a][3]);

    if (tid < 64) {
        float s = 0.f;
        #pragma unroll 8
        for (int i = 0; i < 64; ++i) s += Ks[i][tid];
        CKS[(size_t)blockIdx.x * 64 + tid] = s;
    }
}

// ---------------- exclusive prefix over chunks ----------------
__global__ __launch_bounds__(256) void k_prefix_kv(float* __restrict__ CKV)
{
    const int bh = blockIdx.x >> 4;
    const int p  = ((blockIdx.x & 15) << 8) + threadIdx.x;   // 0..4095
    const size_t base = (size_t)bh * 64 * 4096 + p;
    float v[64];
    #pragma unroll
    for (int c = 0; c < 64; ++c) v[c] = CKV[base + (size_t)c * 4096];
    float acc = 0.f;
    #pragma unroll
    for (int c = 0; c < 64; ++c) { float t = v[c]; CKV[base + (size_t)c * 4096] = acc; acc += t; }
}

__global__ __launch_bounds__(256) void k_prefix_ks(float* __restrict__ CKS)
{
    const int idx = blockIdx.x * 256 + threadIdx.x;  // 0..2047
    const int bh = idx >> 6, d = idx & 63;
    const size_t base = (size_t)bh * 64 * 64 + d;
    float v[64];
    #pragma unroll
    for (int c = 0; c < 64; ++c) v[c] = CKS[base + (size_t)c * 64];
    float acc = 0.f;
    #pragma unroll
    for (int c = 0; c < 64; ++c) { float t = v[c]; CKS[base + (size_t)c * 64] = acc; acc += t; }
}

// ---------------- per-chunk attention output (bf16 in/out) ----------------
// grid 2048 (bh*64 + c), block 256.
__global__ __launch_bounds__(256) void k_attn(
    const u16* __restrict__ Qg, const u16* __restrict__ Kg, const u16* __restrict__ Vg,
    const float* __restrict__ CKV, const float* __restrict__ CKS, u16* __restrict__ AO)
{
    const int tid = threadIdx.x;
    const int tx = tid & 15, ty = tid >> 4;
    const int c  = blockIdx.x & 63;
    const int bh = blockIdx.x >> 6;
    const int b = bh >> 4, h = bh & 15;
    const int row0 = b * 4096 + c * 64;
    const int col  = h * 64;

    __shared__ float Qs[64][68];
    __shared__ float KVs[64][68];     // first K, then V
    __shared__ float AsT[64][64];     // A transposed: AsT[j][i]
    __shared__ float ksumP[64];
    __shared__ float invden[64];

    #pragma unroll
    for (int r = 0; r < 2; ++r) {
        int idx = tid + r * 256;
        int i = idx >> 3, cg = (idx & 7) << 3;
        uint4 qu = *(const uint4*)&Qg[(size_t)(row0 + i) * 1024 + col + cg];
        uint4 ku = *(const uint4*)&Kg[(size_t)(row0 + i) * 1024 + col + cg];
        Qs[i][cg+0]=bflo(qu.x); Qs[i][cg+1]=bfhi(qu.x);
        Qs[i][cg+2]=bflo(qu.y); Qs[i][cg+3]=bfhi(qu.y);
        Qs[i][cg+4]=bflo(qu.z); Qs[i][cg+5]=bfhi(qu.z);
        Qs[i][cg+6]=bflo(qu.w); Qs[i][cg+7]=bfhi(qu.w);
        KVs[i][cg+0]=bflo(ku.x); KVs[i][cg+1]=bfhi(ku.x);
        KVs[i][cg+2]=bflo(ku.y); KVs[i][cg+3]=bfhi(ku.y);
        KVs[i][cg+4]=bflo(ku.z); KVs[i][cg+5]=bfhi(ku.z);
        KVs[i][cg+6]=bflo(ku.w); KVs[i][cg+7]=bfhi(ku.w);
    }
    if (tid < 64) ksumP[tid] = CKS[(size_t)blockIdx.x * 64 + tid];
    __syncthreads();

    // A[i][j] = q_i . k_j  (masked j<=i), stored transposed
    float a[4][4] = {};
    #pragma unroll 4
    for (int d = 0; d < 64; d += 4) {
        float qv[4][4], kv[4][4];
        #pragma unroll
        for (int ii = 0; ii < 4; ++ii) f4a(*(const float4*)&Qs[ty*4 + ii][d], qv[ii]);
        #pragma unroll
        for (int jj = 0; jj < 4; ++jj) f4a(*(const float4*)&KVs[tx*4 + jj][d], kv[jj]);
        #pragma unroll
        for (int ii = 0; ii < 4; ++ii)
            #pragma unroll
            for (int jj = 0; jj < 4; ++jj)
                #pragma unroll
                for (int dd = 0; dd < 4; ++dd)
                    a[ii][jj] = fmaf(qv[ii][dd], kv[jj][dd], a[ii][jj]);
    }
    #pragma unroll
    for (int ii = 0; ii < 4; ++ii)
        #pragma unroll
        for (int jj = 0; jj < 4; ++jj) {
            int i = ty*4 + ii, j = tx*4 + jj;
            AsT[j][i] = (j <= i) ? a[ii][jj] : 0.f;
        }
    __syncthreads();

    // load V over K (K reads done); threads<64 compute denominators
    #pragma unroll
    for (int r = 0; r < 2; ++r) {
        int idx = tid + r * 256;
        int i = idx >> 3, cg = (idx & 7) << 3;
        uint4 vu = *(const uint4*)&Vg[(size_t)(row0 + i) * 1024 + col + cg];
        KVs[i][cg+0]=bflo(vu.x); KVs[i][cg+1]=bfhi(vu.x);
        KVs[i][cg+2]=bflo(vu.y); KVs[i][cg+3]=bfhi(vu.y);
        KVs[i][cg+4]=bflo(vu.z); KVs[i][cg+5]=bfhi(vu.z);
        KVs[i][cg+6]=bflo(vu.w); KVs[i][cg+7]=bfhi(vu.w);
    }
    if (tid < 64) {
        float s = EPSF;
        #pragma unroll 8
        for (int d = 0; d < 64; ++d) s += Qs[tid][d] * ksumP[d];
        #pragma unroll 8
        for (int j = 0; j < 64; ++j) s += AsT[j][tid];   // masked entries are 0
        invden[tid] = 1.f / s;
    }
    __syncthreads();

    // out[i][e] = sum_j A[i][j] V[j][e] + sum_d Q[i][d] St[d][e]
    float o[4][4] = {};
    #pragma unroll 8
    for (int j = 0; j < 64; ++j) {
        float av[4], vv[4];
        f4a(*(const float4*)&AsT[j][ty*4], av);
        f4a(*(const float4*)&KVs[j][tx*4], vv);
        #pragma unroll
        for (int ii = 0; ii < 4; ++ii)
            #pragma unroll
            for (int jj = 0; jj < 4; ++jj)
                o[ii][jj] = fmaf(av[ii], vv[jj], o[ii][jj]);
    }
    const float* St = &CKV[(size_t)blockIdx.x * 4096];
    #pragma unroll 4
    for (int d = 0; d < 64; ++d) {
        float sv[4];
        f4a(*(const float4*)&St[d * 64 + tx*4], sv);
        float qd[4];
        #pragma unroll
        for (int ii = 0; ii < 4; ++ii) qd[ii] = Qs[ty*4 + ii][d];
        #pragma unroll
        for (int ii = 0; ii < 4; ++ii)
            #pragma unroll
            for (int jj = 0; jj < 4; ++jj)
                o[ii][jj] = fmaf(qd[ii], sv[jj], o[ii][jj]);
    }
    #pragma unroll
    for (int ii = 0; ii < 4; ++ii) {
        int i = ty*4 + ii;
        float id = invden[i];
        u32 p0 = (u32)f2bf(o[ii][0]*id) | ((u32)f2bf(o[ii][1]*id) << 16);
        u32 p1 = (u32)f2bf(o[ii][2]*id) | ((u32)f2bf(o[ii][3]*id) << 16);
        *(uint2*)&AO[(size_t)(row0 + i) * 1024 + col + tx*4] = make_uint2(p0, p1);
    }
}

extern "C" void kernel_launch(void* const* d_in, const int* in_sizes, int n_in,
                              void* d_out, int out_size, void* d_ws, size_t ws_size,
                              hipStream_t stream)
{
    const float* x  = (const float*)d_in[0];
    const float* Wq = (const float*)d_in[1];
    const float* Wk = (const float*)d_in[2];
    const float* Wv = (const float*)d_in[3];
    const float* Wo = (const float*)d_in[4];
    float* out = (float*)d_out;

    char* w = (char*)d_ws;
    // byte offsets, all 16B aligned; total ~104.5 MiB (< round-1's 134.7 MiB, proven to fit)
    float* CKV = (float*)(w);                       // 33554432 B
    float* CKS = (float*)(w + 33554432);            //   524288 B
    u16*   Qb  = (u16*)  (w + 34078720);            // 16777216 B
    u16*   Kb  = (u16*)  (w + 50855936);            // 16777216 B
    u16*   Vb  = (u16*)  (w + 67633152);            // 16777216 B
    u16*   xb  = (u16*)  (w + 84410368);            // 16777216 B (aliased AOb)
    u16*   AOb = xb;                                // xb dead after QKV GEMMs
    u16*   Wqb = (u16*)  (w + 101187584);           //  2097152 B
    u16*   Wkb = (u16*)  (w + 103284736);
    u16*   Wvb = (u16*)  (w + 105381888);
    u16*   Wob = (u16*)  (w + 107479040);           // end: 109576192 B

    k_cast5     <<<6144,        256, 0, stream>>>(x, Wq, Wk, Wv, Wo, xb, Wqb, Wkb, Wvb, Wob);
    k_gemm_nt<1><<<dim3(64, 8), 256, 0, stream>>>(xb, Wqb, Qb);
    k_gemm_nt<1><<<dim3(64, 8), 256, 0, stream>>>(xb, Wkb, Kb);
    k_gemm_nt<2><<<dim3(64, 8), 256, 0, stream>>>(xb, Wvb, Vb);
    k_chunksums <<<2048,        256, 0, stream>>>(Kb, Vb, CKV, CKS);
    k_prefix_kv <<<512,         256, 0, stream>>>(CKV);
    k_prefix_ks <<<8,           256, 0, stream>>>(CKS);
    k_attn      <<<2048,        256, 0, stream>>>(Qb, Kb, Vb, CKV, CKS, AOb);
    k_gemm_nt<3><<<dim3(64, 8), 256, 0, stream>>>(AOb, Wob, (void*)out);
}

// Round 3
// 156.121 us; speedup vs baseline: 6.2961x; 1.3762x over previous
//
#include <hip/hip_runtime.h>
#include <math.h>

// LinearAttention: B=2, S=4096, D=1024, H=16, Dh=64
// Round 3: MFMA-ized chunk attention + fused QKV GEMM.
//   1) k_cast5     : x -> xb ; Wq|Wk|Wv -> Wcatb (concat) ; Wo -> Wob   (bf16)
//   2) k_gemm_qkv  : QKVb = [elu1(x Wq^T) | elu1(x Wk^T) | x Wv^T]  (MFMA, fused)
//   3) k_chunksums : CKV[bh][c][e][d] = sum_i K[i][d] V[i][e] (TRANSPOSED), CKS
//   4) k_prefix_kv : exclusive prefix over chunks -> bf16 CKVp ; k_prefix_ks fp32
//   5) k_attn2     : MFMA per-chunk: P=mask(QK^T); O=(P V + Q St)/den -> bf16 AOb
//   6) k_gemm_out  : d_out = AOb Wo^T (fp32 out)

#define EPSF 1e-8f

typedef unsigned short u16;
typedef unsigned int   u32;
typedef __attribute__((ext_vector_type(8))) short short8v;
typedef __attribute__((ext_vector_type(4))) float f32x4;

__device__ __forceinline__ float elu1(float x){ return x > 0.f ? x + 1.f : __expf(x); }
__device__ __forceinline__ u16 f2bf(float f){
    union{float f; u32 i;} c; c.f = f;
    u32 i = c.i + 0x7FFFu + ((c.i >> 16) & 1u);   // RNE
    return (u16)(i >> 16);
}
__device__ __forceinline__ float bflo(u32 v){ union{u32 i; float f;} c; c.i = v << 16; return c.f; }
__device__ __forceinline__ float bfhi(u32 v){ union{u32 i; float f;} c; c.i = v & 0xffff0000u; return c.f; }
__device__ __forceinline__ void f4a(float4 v, float* a){ a[0]=v.x; a[1]=v.y; a[2]=v.z; a[3]=v.w; }

__device__ __forceinline__ void gload16(const void* g, void* l){
    __builtin_amdgcn_global_load_lds((const __attribute__((address_space(1))) u32*)g,
                                     (__attribute__((address_space(3))) u32*)l, 16, 0, 0);
}

// ---------------- Kernel 0: cast fp32 -> bf16 ----------------
__global__ __launch_bounds__(256) void k_cast5(
    const float* __restrict__ x,  const float* __restrict__ wq,
    const float* __restrict__ wk, const float* __restrict__ wv,
    const float* __restrict__ wo,
    u16* __restrict__ xb, u16* __restrict__ wcat, u16* __restrict__ wob)
{
    size_t i8 = ((size_t)blockIdx.x * 256 + threadIdx.x) * 8;
    const float* s; u16* d; size_t off;
    if      (i8 <  8388608) { s = x;  d = xb;            off = i8; }
    else if (i8 <  9437184) { s = wq; d = wcat;          off = i8 - 8388608; }
    else if (i8 < 10485760) { s = wk; d = wcat + 1048576; off = i8 - 9437184; }
    else if (i8 < 11534336) { s = wv; d = wcat + 2097152; off = i8 - 10485760; }
    else                    { s = wo; d = wob;           off = i8 - 11534336; }
    float4 a = *(const float4*)&s[off];
    float4 b = *(const float4*)&s[off + 4];
    uint4 p;
    p.x = (u32)f2bf(a.x) | ((u32)f2bf(a.y) << 16);
    p.y = (u32)f2bf(a.z) | ((u32)f2bf(a.w) << 16);
    p.z = (u32)f2bf(b.x) | ((u32)f2bf(b.y) << 16);
    p.w = (u32)f2bf(b.z) | ((u32)f2bf(b.w) << 16);
    *(uint4*)&d[off] = p;
}

// ---------------- fused QKV MFMA GEMM-NT ----------------
// C[8192][3072-as-3-matrices] = A[8192][1024] * Wcat[3072][1024]^T
// grid 1536 (1D, XCD-chunk-swizzled, bx-major), block 256.
__global__ __launch_bounds__(256) void k_gemm_qkv(
    const u16* __restrict__ A, const u16* __restrict__ W, u16* __restrict__ C)
{
    const int id  = blockIdx.x;
    const int nid = (id & 7) * 192 + (id >> 3);   // 1536 = 8*192, bijective
    const int bx  = nid / 24;                     // m-tile 0..63
    const int by  = nid % 24;                     // n-tile 0..23 (into 3072)
    const int matrix = by >> 3;                   // 0:Q 1:K 2:V
    const bool do_elu = matrix < 2;
    u16* out = C + (size_t)matrix * 8388608;
    const int m0 = bx * 128;
    const int n0 = by * 128;                      // row into Wcat
    const int col0 = (by & 7) * 128;              // col into output matrix

    __shared__ __align__(16) u16 As[128 * 32];
    __shared__ __align__(16) u16 Bs[128 * 32];
    const int tid = threadIdx.x;
    const int l   = tid & 63;
    const int wv  = tid >> 6;
    const int wr  = (wv >> 1) * 64;
    const int wc  = (wv & 1) * 64;
    const int srow  = tid >> 2;
    const int skoff = (tid & 3) * 8;

    f32x4 acc[4][4];
    #pragma unroll
    for (int m = 0; m < 4; ++m)
        #pragma unroll
        for (int n = 0; n < 4; ++n) acc[m][n] = (f32x4){0.f, 0.f, 0.f, 0.f};

    for (int kt = 0; kt < 1024; kt += 32) {
        __syncthreads();
        #pragma unroll
        for (int h = 0; h < 2; ++h)
            gload16(&A[(size_t)(m0 + h*64 + srow) * 1024 + kt + skoff],
                    (char*)As + h*4096 + wv*1024);
        #pragma unroll
        for (int h = 0; h < 2; ++h)
            gload16(&W[(size_t)(n0 + h*64 + srow) * 1024 + kt + skoff],
                    (char*)Bs + h*4096 + wv*1024);
        __syncthreads();

        short8v a[4], b[4];
        #pragma unroll
        for (int m = 0; m < 4; ++m)
            a[m] = *(const short8v*)&As[(wr + m*16 + (l & 15)) * 32 + (l >> 4) * 8];
        #pragma unroll
        for (int n = 0; n < 4; ++n)
            b[n] = *(const short8v*)&Bs[(wc + n*16 + (l & 15)) * 32 + (l >> 4) * 8];
        #pragma unroll
        for (int m = 0; m < 4; ++m)
            #pragma unroll
            for (int n = 0; n < 4; ++n)
                acc[m][n] = __builtin_amdgcn_mfma_f32_16x16x32_bf16(a[m], b[n], acc[m][n], 0, 0, 0);
    }

    const int r0 = m0 + wr + (l >> 4) * 4;
    const int c0 = col0 + wc + (l & 15);
    #pragma unroll
    for (int m = 0; m < 4; ++m)
        #pragma unroll
        for (int n = 0; n < 4; ++n)
            #pragma unroll
            for (int r = 0; r < 4; ++r) {
                float v = acc[m][n][r];
                if (do_elu) v = elu1(v);
                out[(size_t)(r0 + m*16 + r) * 1024 + c0 + n*16] = f2bf(v);
            }
}

// ---------------- final output GEMM (f32 out) ----------------
__global__ __launch_bounds__(256) void k_gemm_out(
    const u16* __restrict__ A, const u16* __restrict__ W, float* __restrict__ C)
{
    const int id  = blockIdx.x;
    const int nid = (id & 7) * 64 + (id >> 3);    // 512 = 8*64
    const int bx  = nid >> 3;
    const int by  = nid & 7;
    const int m0 = bx * 128;
    const int n0 = by * 128;

    __shared__ __align__(16) u16 As[128 * 32];
    __shared__ __align__(16) u16 Bs[128 * 32];
    const int tid = threadIdx.x;
    const int l   = tid & 63;
    const int wv  = tid >> 6;
    const int wr  = (wv >> 1) * 64;
    const int wc  = (wv & 1) * 64;
    const int srow  = tid >> 2;
    const int skoff = (tid & 3) * 8;

    f32x4 acc[4][4];
    #pragma unroll
    for (int m = 0; m < 4; ++m)
        #pragma unroll
        for (int n = 0; n < 4; ++n) acc[m][n] = (f32x4){0.f, 0.f, 0.f, 0.f};

    for (int kt = 0; kt < 1024; kt += 32) {
        __syncthreads();
        #pragma unroll
        for (int h = 0; h < 2; ++h)
            gload16(&A[(size_t)(m0 + h*64 + srow) * 1024 + kt + skoff],
                    (char*)As + h*4096 + wv*1024);
        #pragma unroll
        for (int h = 0; h < 2; ++h)
            gload16(&W[(size_t)(n0 + h*64 + srow) * 1024 + kt + skoff],
                    (char*)Bs + h*4096 + wv*1024);
        __syncthreads();

        short8v a[4], b[4];
        #pragma unroll
        for (int m = 0; m < 4; ++m)
            a[m] = *(const short8v*)&As[(wr + m*16 + (l & 15)) * 32 + (l >> 4) * 8];
        #pragma unroll
        for (int n = 0; n < 4; ++n)
            b[n] = *(const short8v*)&Bs[(wc + n*16 + (l & 15)) * 32 + (l >> 4) * 8];
        #pragma unroll
        for (int m = 0; m < 4; ++m)
            #pragma unroll
            for (int n = 0; n < 4; ++n)
                acc[m][n] = __builtin_amdgcn_mfma_f32_16x16x32_bf16(a[m], b[n], acc[m][n], 0, 0, 0);
    }

    const int r0 = m0 + wr + (l >> 4) * 4;
    const int c0 = n0 + wc + (l & 15);
    #pragma unroll
    for (int m = 0; m < 4; ++m)
        #pragma unroll
        for (int n = 0; n < 4; ++n)
            #pragma unroll
            for (int r = 0; r < 4; ++r)
                C[(size_t)(r0 + m*16 + r) * 1024 + c0 + n*16] = acc[m][n][r];
}

// ---------------- per-chunk KV sums (bf16 in, fp32 out, TRANSPOSED [e][d]) ----------------
__global__ __launch_bounds__(256) void k_chunksums(
    const u16* __restrict__ Kg, const u16* __restrict__ Vg,
    float* __restrict__ CKVt, float* __restrict__ CKS)
{
    const int tid = threadIdx.x;
    const int tx = tid & 15, ty = tid >> 4;
    const int c  = blockIdx.x & 63;
    const int bh = blockIdx.x >> 6;
    const int b = bh >> 4, h = bh & 15;
    const int row0 = b * 4096 + c * 64;
    const int col  = h * 64;

    __shared__ float Ks[64][68];
    __shared__ float Vs[64][68];

    #pragma unroll
    for (int r = 0; r < 2; ++r) {
        int idx = tid + r * 256;
        int i = idx >> 3, cg = (idx & 7) << 3;
        uint4 ku = *(const uint4*)&Kg[(size_t)(row0 + i) * 1024 + col + cg];
        uint4 vu = *(const uint4*)&Vg[(size_t)(row0 + i) * 1024 + col + cg];
        Ks[i][cg+0]=bflo(ku.x); Ks[i][cg+1]=bfhi(ku.x);
        Ks[i][cg+2]=bflo(ku.y); Ks[i][cg+3]=bfhi(ku.y);
        Ks[i][cg+4]=bflo(ku.z); Ks[i][cg+5]=bfhi(ku.z);
        Ks[i][cg+6]=bflo(ku.w); Ks[i][cg+7]=bfhi(ku.w);
        Vs[i][cg+0]=bflo(vu.x); Vs[i][cg+1]=bfhi(vu.x);
        Vs[i][cg+2]=bflo(vu.y); Vs[i][cg+3]=bfhi(vu.y);
        Vs[i][cg+4]=bflo(vu.z); Vs[i][cg+5]=bfhi(vu.z);
        Vs[i][cg+6]=bflo(vu.w); Vs[i][cg+7]=bfhi(vu.w);
    }
    __syncthreads();

    float acc[4][4] = {};   // acc[a=d-sub][e-sub]
    #pragma unroll 8
    for (int i = 0; i < 64; ++i) {
        float kv[4], vv[4];
        f4a(*(const float4*)&Ks[i][ty*4], kv);
        f4a(*(const float4*)&Vs[i][tx*4], vv);
        #pragma unroll
        for (int a = 0; a < 4; ++a)
            #pragma unroll
            for (int e = 0; e < 4; ++e)
                acc[a][e] = fmaf(kv[a], vv[e], acc[a][e]);
    }
    // transposed write: CKVt[e][d], d contiguous
    float* ckv = &CKVt[(size_t)blockIdx.x * 4096];
    #pragma unroll
    for (int e = 0; e < 4; ++e)
        *(float4*)&ckv[(tx*4 + e) * 64 + ty*4] =
            make_float4(acc[0][e], acc[1][e], acc[2][e], acc[3][e]);

    if (tid < 64) {
        float s = 0.f;
        #pragma unroll 8
        for (int i = 0; i < 64; ++i) s += Ks[i][tid];
        CKS[(size_t)blockIdx.x * 64 + tid] = s;
    }
}

// ---------------- exclusive prefix over chunks: fp32 in -> bf16 out ----------------
__global__ __launch_bounds__(256) void k_prefix_kv(
    const float* __restrict__ CKVt, u16* __restrict__ CKVp)
{
    const int bh = blockIdx.x >> 4;
    const int p  = ((blockIdx.x & 15) << 8) + threadIdx.x;   // 0..4095
    const size_t base = (size_t)bh * 64 * 4096 + p;
    float acc = 0.f;
    #pragma unroll
    for (int c = 0; c < 64; ++c) {
        float t = CKVt[base + (size_t)c * 4096];
        CKVp[base + (size_t)c * 4096] = f2bf(acc);
        acc += t;
    }
}

__global__ __launch_bounds__(256) void k_prefix_ks(float* __restrict__ CKS)
{
    const int idx = blockIdx.x * 256 + threadIdx.x;  // 0..2047
    const int bh = idx >> 6, d = idx & 63;
    const size_t base = (size_t)bh * 64 * 64 + d;
    float v[64];
    #pragma unroll
    for (int c = 0; c < 64; ++c) v[c] = CKS[base + (size_t)c * 64];
    float acc = 0.f;
    #pragma unroll
    for (int c = 0; c < 64; ++c) { float t = v[c]; CKS[base + (size_t)c * 64] = acc; acc += t; }
}

// ---------------- MFMA per-chunk attention ----------------
// grid 2048 (bh*64 + c), block 256 = 4 waves; wave w owns output rows [16w,16w+16).
#define LSTR 72   // LDS row stride in elements (144B, 16B-aligned)
__global__ __launch_bounds__(256) void k_attn2(
    const u16* __restrict__ Qg, const u16* __restrict__ Kg, const u16* __restrict__ Vg,
    const u16* __restrict__ Stg,   // CKVp bf16 [bh][c][e][d]
    const float* __restrict__ KSg, // CKS fp32 [bh][c][d] (exclusive prefix)
    u16* __restrict__ AO)
{
    const int tid = threadIdx.x;
    const int l = tid & 63;
    const int w = tid >> 6;
    const int c  = blockIdx.x & 63;
    const int bh = blockIdx.x >> 6;
    const int row0 = (bh >> 4) * 4096 + c * 64;
    const int col  = (bh & 15) * 64;

    __shared__ __align__(16) u16 Qs [64 * LSTR];
    __shared__ __align__(16) u16 Ks [64 * LSTR];
    __shared__ __align__(16) u16 Vt [64 * LSTR];   // Vt[e][j] = V[j][e]
    __shared__ __align__(16) u16 Sts[64 * LSTR];   // St^T[e][d]
    __shared__ __align__(16) u16 Pl [64 * LSTR];   // masked P[i][j] bf16; reused for output
    __shared__ float ksumF[64];
    __shared__ float invdenL[64];

    // ---- stage Q, K, St (straight) and V (transposed) ----
    #pragma unroll
    for (int r = 0; r < 2; ++r) {
        int idx = tid + r * 256;
        int i = idx >> 3, cg = (idx & 7) << 3;
        *(uint4*)&Qs [i*LSTR + cg] = *(const uint4*)&Qg [(size_t)(row0 + i) * 1024 + col + cg];
        *(uint4*)&Ks [i*LSTR + cg] = *(const uint4*)&Kg [(size_t)(row0 + i) * 1024 + col + cg];
        *(uint4*)&Sts[i*LSTR + cg] = *(const uint4*)&Stg[(size_t)blockIdx.x * 4096 + i * 64 + cg];
        uint4 vu = *(const uint4*)&Vg[(size_t)(row0 + i) * 1024 + col + cg];
        Vt[(cg+0)*LSTR + i] = (u16)(vu.x & 0xffff);
        Vt[(cg+1)*LSTR + i] = (u16)(vu.x >> 16);
        Vt[(cg+2)*LSTR + i] = (u16)(vu.y & 0xffff);
        Vt[(cg+3)*LSTR + i] = (u16)(vu.y >> 16);
        Vt[(cg+4)*LSTR + i] = (u16)(vu.z & 0xffff);
        Vt[(cg+5)*LSTR + i] = (u16)(vu.z >> 16);
        Vt[(cg+6)*LSTR + i] = (u16)(vu.w & 0xffff);
        Vt[(cg+7)*LSTR + i] = (u16)(vu.w >> 16);
    }
    if (tid < 64) ksumF[tid] = KSg[(size_t)blockIdx.x * 64 + tid];
    __syncthreads();

    const int li = l & 15;       // lane row-in-strip / B-operand row
    const int lg = l >> 4;       // lane k-group
    const int i_row = w * 16 + li;   // this lane's P/den row

    // ---- QK^T swapped: C[j][i] = mfma(a=K_frag(j), b=Q_frag(i-strip)) ----
    short8v bq[2];
    #pragma unroll
    for (int kc = 0; kc < 2; ++kc)
        bq[kc] = *(const short8v*)&Qs[i_row * LSTR + lg*8 + kc*32];

    float den = EPSF;
    #pragma unroll
    for (int mj = 0; mj < 4; ++mj) {
        f32x4 sacc = (f32x4){0.f, 0.f, 0.f, 0.f};
        #pragma unroll
        for (int kc = 0; kc < 2; ++kc) {
            short8v ak = *(const short8v*)&Ks[(mj*16 + li) * LSTR + lg*8 + kc*32];
            sacc = __builtin_amdgcn_mfma_f32_16x16x32_bf16(ak, bq[kc], sacc, 0, 0, 0);
        }
        const int jbase = mj*16 + lg*4;
        float pv[4];
        #pragma unroll
        for (int r = 0; r < 4; ++r) {
            float v = sacc[r];
            v = (jbase + r <= i_row - w*16 + w*16) ? v : 0.f;   // j <= i (same chunk-local)
            v = (jbase + r <= i_row) ? v : 0.f;
            den += v;
            pv[r] = v;
        }
        u32 lo = (u32)f2bf(pv[0]) | ((u32)f2bf(pv[1]) << 16);
        u32 hi = (u32)f2bf(pv[2]) | ((u32)f2bf(pv[3]) << 16);
        *(uint2*)&Pl[i_row * LSTR + jbase] = make_uint2(lo, hi);
    }

    // ---- q . ksum_prefix partial (d-range per lane group) ----
    {
        const int d0 = lg * 16;
        uint4 q1 = *(const uint4*)&Qs[i_row * LSTR + d0];
        uint4 q2 = *(const uint4*)&Qs[i_row * LSTR + d0 + 8];
        den += bflo(q1.x)*ksumF[d0+0] + bfhi(q1.x)*ksumF[d0+1]
             + bflo(q1.y)*ksumF[d0+2] + bfhi(q1.y)*ksumF[d0+3]
             + bflo(q1.z)*ksumF[d0+4] + bfhi(q1.z)*ksumF[d0+5]
             + bflo(q1.w)*ksumF[d0+6] + bfhi(q1.w)*ksumF[d0+7]
             + bflo(q2.x)*ksumF[d0+8] + bfhi(q2.x)*ksumF[d0+9]
             + bflo(q2.y)*ksumF[d0+10]+ bfhi(q2.y)*ksumF[d0+11]
             + bflo(q2.z)*ksumF[d0+12]+ bfhi(q2.z)*ksumF[d0+13]
             + bflo(q2.w)*ksumF[d0+14]+ bfhi(q2.w)*ksumF[d0+15];
    }
    // reduce across the 4 lane-groups (same i, different j-quads / d-ranges)
    den += __shfl_xor(den, 16);
    den += __shfl_xor(den, 32);
    if (l < 16) invdenL[w*16 + l] = 1.f / den;

    // ---- PV + Q.St : O[i][e] ----
    f32x4 oacc[4];
    #pragma unroll
    for (int ne = 0; ne < 4; ++ne) oacc[ne] = (f32x4){0.f, 0.f, 0.f, 0.f};
    #pragma unroll
    for (int kc = 0; kc < 2; ++kc) {
        short8v ap = *(const short8v*)&Pl[i_row * LSTR + lg*8 + kc*32];
        short8v aq = bq[kc];
        #pragma unroll
        for (int ne = 0; ne < 4; ++ne) {
            short8v bv = *(const short8v*)&Vt [(ne*16 + li) * LSTR + lg*8 + kc*32];
            short8v bs = *(const short8v*)&Sts[(ne*16 + li) * LSTR + lg*8 + kc*32];
            oacc[ne] = __builtin_amdgcn_mfma_f32_16x16x32_bf16(ap, bv, oacc[ne], 0, 0, 0);
            oacc[ne] = __builtin_amdgcn_mfma_f32_16x16x32_bf16(aq, bs, oacc[ne], 0, 0, 0);
        }
    }

    // ---- epilogue: scale rows by invden, transpose through LDS (reuse Pl), store ----
    float inv[4];
    #pragma unroll
    for (int r = 0; r < 4; ++r) inv[r] = invdenL[w*16 + lg*4 + r];
    #pragma unroll
    for (int ne = 0; ne < 4; ++ne)
        #pragma unroll
        for (int r = 0; r < 4; ++r)
            Pl[(w*16 + lg*4 + r) * LSTR + ne*16 + li] = f2bf(oacc[ne][r] * inv[r]);

    // wave-local rows -> coalesced global write (no barrier needed: own rows only)
    #pragma unroll
    for (int p = 0; p < 2; ++p) {
        int idx2 = l + p * 64;                 // 0..127 over 16 rows x 64 cols
        int ro = w*16 + (idx2 >> 3), cg = (idx2 & 7) << 3;
        *(uint4*)&AO[(size_t)(row0 + ro) * 1024 + col + cg] = *(const uint4*)&Pl[ro*LSTR + cg];
    }
}

extern "C" void kernel_launch(void* const* d_in, const int* in_sizes, int n_in,
                              void* d_out, int out_size, void* d_ws, size_t ws_size,
                              hipStream_t stream)
{
    const float* x  = (const float*)d_in[0];
    const float* Wq = (const float*)d_in[1];
    const float* Wk = (const float*)d_in[2];
    const float* Wv = (const float*)d_in[3];
    const float* Wo = (const float*)d_in[4];
    float* out = (float*)d_out;

    char* w = (char*)d_ws;
    // byte offsets (16B aligned), total ~126.4 MiB (< round-1's 134.7 MiB, proven to fit)
    u16*   QKVb = (u16*)(w);                        // 3 x 16777216 B = 50331648
    u16*   Qb   = QKVb;
    u16*   Kb   = QKVb + 8388608;
    u16*   Vb   = QKVb + 16777216;
    u16*   xb   = (u16*)(w + 50331648);             // 16777216 B (aliased AOb)
    u16*   AOb  = xb;
    u16*   Wcat = (u16*)(w + 67108864);             //  6291456 B
    u16*   Wob  = (u16*)(w + 73400320);             //  2097152 B
    float* CKV  = (float*)(w + 75497472);           // 33554432 B
    u16*   CKVp = (u16*)(w + 109051904);            // 16777216 B
    float* CKS  = (float*)(w + 125829120);          //   524288 B  -> end 126353408

    k_cast5    <<<6144, 256, 0, stream>>>(x, Wq, Wk, Wv, Wo, xb, Wcat, Wob);
    k_gemm_qkv <<<1536, 256, 0, stream>>>(xb, Wcat, QKVb);
    k_chunksums<<<2048, 256, 0, stream>>>(Kb, Vb, CKV, CKS);
    k_prefix_kv<<<512,  256, 0, stream>>>(CKV, CKVp);
    k_prefix_ks<<<8,    256, 0, stream>>>(CKS);
    k_attn2    <<<2048, 256, 0, stream>>>(Qb, Kb, Vb, CKVp, CKS, AOb);
    k_gemm_out <<<512,  256, 0, stream>>>(AOb, Wob, out);
}

// Round 4
// 142.600 us; speedup vs baseline: 6.8931x; 1.0948x over previous
//
#include <hip/hip_runtime.h>
#include <math.h>

// LinearAttention: B=2, S=4096, D=1024, H=16, Dh=64
// Round 4: GEMMs -> pipelined MFMA template (BM128xBN256, BK=64 as 2 k-planes,
// counted vmcnt(6) never-drain, LDS slot-swizzle, setprio). Attention chain
// unchanged from round 3.

#define EPSF 1e-8f

typedef unsigned short u16;
typedef unsigned int   u32;
typedef __attribute__((ext_vector_type(8))) short short8v;
typedef __attribute__((ext_vector_type(4))) float f32x4;

__device__ __forceinline__ float elu1(float x){ return x > 0.f ? x + 1.f : __expf(x); }
__device__ __forceinline__ u16 f2bf(float f){
    union{float f; u32 i;} c; c.f = f;
    u32 i = c.i + 0x7FFFu + ((c.i >> 16) & 1u);   // RNE
    return (u16)(i >> 16);
}
__device__ __forceinline__ float bflo(u32 v){ union{u32 i; float f;} c; c.i = v << 16; return c.f; }
__device__ __forceinline__ float bfhi(u32 v){ union{u32 i; float f;} c; c.i = v & 0xffff0000u; return c.f; }
__device__ __forceinline__ void f4a(float4 v, float* a){ a[0]=v.x; a[1]=v.y; a[2]=v.z; a[3]=v.w; }

__device__ __forceinline__ void gload16(const void* g, void* l){
    __builtin_amdgcn_global_load_lds((const __attribute__((address_space(1))) u32*)g,
                                     (__attribute__((address_space(3))) u32*)l, 16, 0, 0);
}

// ---------------- Kernel 0: cast fp32 -> bf16 ----------------
__global__ __launch_bounds__(256) void k_cast5(
    const float* __restrict__ x,  const float* __restrict__ wq,
    const float* __restrict__ wk, const float* __restrict__ wv,
    const float* __restrict__ wo,
    u16* __restrict__ xb, u16* __restrict__ wcat, u16* __restrict__ wob)
{
    size_t i8 = ((size_t)blockIdx.x * 256 + threadIdx.x) * 8;
    const float* s; u16* d; size_t off;
    if      (i8 <  8388608) { s = x;  d = xb;            off = i8; }
    else if (i8 <  9437184) { s = wq; d = wcat;          off = i8 - 8388608; }
    else if (i8 < 10485760) { s = wk; d = wcat + 1048576; off = i8 - 9437184; }
    else if (i8 < 11534336) { s = wv; d = wcat + 2097152; off = i8 - 10485760; }
    else                    { s = wo; d = wob;           off = i8 - 11534336; }
    float4 a = *(const float4*)&s[off];
    float4 b = *(const float4*)&s[off + 4];
    uint4 p;
    p.x = (u32)f2bf(a.x) | ((u32)f2bf(a.y) << 16);
    p.y = (u32)f2bf(a.z) | ((u32)f2bf(a.w) << 16);
    p.z = (u32)f2bf(b.x) | ((u32)f2bf(b.y) << 16);
    p.w = (u32)f2bf(b.z) | ((u32)f2bf(b.w) << 16);
    *(uint4*)&d[off] = p;
}

// ---------------- Pipelined MFMA GEMM-NT ----------------
// C[M][*] = A[M][1024] * W[N][1024]^T. BM=128, BN=256, BK=64 (2 k-planes of 32).
// 8 waves (2m x 4n), wave tile 64x64, acc[4][4]. 96 KiB dynamic LDS:
//   per buf (48 KiB): A-plane[kh] 8 KiB @ buf*49152 + kh*8192   (128 rows x 32k)
//                     B-plane[kh] 16 KiB @ buf*49152+16384+kh*16384 (256 rows x 32k)
// Plane layout: row-pairs share a 128B line; 16B slot s = ((row&1)*4+kg)^(line&7).
// -> a wave's frag ds_read_b128 hits 64 distinct 16B slots (zero bank conflict).
// Staging: linear LDS dest (global_load_lds), INVERSE-swizzled global source.
// Schedule per phase: ds_read frags | issue 3 gloads | 16 MFMA | vmcnt(6) | s_barrier.
// k-plane ring audit (steady state): plane staged in phase p is read in p+2 and
// its LDS slot was last read in p-1 => clobber-free; vmcnt(6)=2 phases in flight.
// Tail iteration tightens to vmcnt(3)/vmcnt(0). No vmcnt(0) in the main loop.
#define AOFF(BUF,KH) ((BUF)*49152 + (KH)*8192)
#define BOFF(BUF,KH) ((BUF)*49152 + 16384 + (KH)*16384)

#define ST(BUF, KT, KH) { \
    gload16(Ag + (size_t)(m0 + sRow)*1024 + (KT)*64 + (KH)*32 + sKg, dsm + AOFF(BUF,KH) + wvv*1024); \
    gload16(Wg + (size_t)(n0 + sRow)*1024 + (KT)*64 + (KH)*32 + sKg, dsm + BOFF(BUF,KH) + wvv*1024); \
    gload16(Wg + (size_t)(n0 + 128 + sRow)*1024 + (KT)*64 + (KH)*32 + sKg, dsm + BOFF(BUF,KH) + 8192 + wvv*1024); }

#define PH(BUF, KH, STCODE, CNT) { \
    short8v a[4], b[4]; \
    const char* Ab = dsm + AOFF(BUF,KH); \
    const char* Bb = dsm + BOFF(BUF,KH); \
    _Pragma("unroll") for (int m = 0; m < 4; ++m) a[m] = *(const short8v*)(Ab + offA[m]); \
    _Pragma("unroll") for (int n = 0; n < 4; ++n) b[n] = *(const short8v*)(Bb + offB[n]); \
    STCODE; \
    __builtin_amdgcn_s_setprio(1); \
    _Pragma("unroll") for (int m = 0; m < 4; ++m) \
        _Pragma("unroll") for (int n = 0; n < 4; ++n) \
            acc[m][n] = __builtin_amdgcn_mfma_f32_16x16x32_bf16(a[m], b[n], acc[m][n], 0, 0, 0); \
    __builtin_amdgcn_s_setprio(0); \
    asm volatile("s_waitcnt vmcnt(" #CNT ")" ::: "memory"); \
    __builtin_amdgcn_s_barrier(); }

// MODE 1: fused QKV (bf16 out, elu on Q/K matrices). MODE 3: f32 out.
template<int MODE, int NBY>
__global__ __launch_bounds__(512, 2) void k_gemm5(
    const u16* __restrict__ Ag, const u16* __restrict__ Wg, void* __restrict__ Cv)
{
    extern __shared__ char dsm[];
    const int nid = (blockIdx.x & 7) * ((64 * NBY) >> 3) + (blockIdx.x >> 3); // XCD chunk swizzle
    const int bx  = nid / NBY;
    const int by  = nid % NBY;
    const int m0  = bx * 128;
    const int n0  = by * 256;

    const int tid = threadIdx.x;
    const int l   = tid & 63;
    const int wid = tid >> 6;
    const int wm  = wid >> 2;      // 0..1
    const int wn  = wid & 3;       // 0..3
    const int li  = l & 15;
    const int kgi = l >> 4;

    // fragment read byte-offsets within a plane (slot-swizzled)
    int offA[4], offB[4];
    #pragma unroll
    for (int m = 0; m < 4; ++m) {
        int ra = wm*64 + m*16 + li;
        offA[m] = (ra >> 1)*128 + (((((ra & 1) << 2) | kgi) ^ ((ra >> 1) & 7)) << 4);
        int rb = wn*64 + m*16 + li;
        offB[m] = (rb >> 1)*128 + (((((rb & 1) << 2) | kgi) ^ ((rb >> 1) & 7)) << 4);
    }
    // staging: inverse-swizzled global source for linear LDS dest
    const int wvv  = wid;
    const int sx   = (l & 7) ^ (l >> 3);
    const int sRow = 2*(wvv*8 + (l >> 3)) + (sx >> 2);   // 0..127
    const int sKg  = (sx & 3) * 8;                       // element offset

    f32x4 acc[4][4];
    #pragma unroll
    for (int m = 0; m < 4; ++m)
        #pragma unroll
        for (int n = 0; n < 4; ++n) acc[m][n] = (f32x4){0.f, 0.f, 0.f, 0.f};

    // prologue: tile0 (both planes) + tile1 plane0
    ST(0, 0, 0); ST(0, 0, 1); ST(1, 1, 0);
    asm volatile("s_waitcnt vmcnt(6)" ::: "memory");
    __builtin_amdgcn_s_barrier();

    #pragma unroll 1
    for (int it = 0; it < 7; ++it) {
        const int T = it * 2;
        PH(0, 0, ST(1, T+1, 1), 6);
        PH(0, 1, ST(0, T+2, 0), 6);
        PH(1, 0, ST(0, T+2, 1), 6);
        PH(1, 1, ST(1, T+3, 0), 6);
    }
    // tail (tiles 14,15): stage only 15.kh1; tighten counts
    PH(0, 0, ST(1, 15, 1), 6);
    PH(0, 1, {}, 3);
    PH(1, 0, {}, 0);
    {   // last phase: no wait/barrier needed after
        short8v a[4], b[4];
        const char* Ab = dsm + AOFF(1,1);
        const char* Bb = dsm + BOFF(1,1);
        #pragma unroll
        for (int m = 0; m < 4; ++m) a[m] = *(const short8v*)(Ab + offA[m]);
        #pragma unroll
        for (int n = 0; n < 4; ++n) b[n] = *(const short8v*)(Bb + offB[n]);
        #pragma unroll
        for (int m = 0; m < 4; ++m)
            #pragma unroll
            for (int n = 0; n < 4; ++n)
                acc[m][n] = __builtin_amdgcn_mfma_f32_16x16x32_bf16(a[m], b[n], acc[m][n], 0, 0, 0);
    }

    // epilogue. C/D layout: col = lane&15, row = (lane>>4)*4 + reg
    const int r0 = m0 + wm*64 + (l >> 4) * 4;
    if (MODE == 1) {
        const int matrix = by >> 2;                 // 0:Q 1:K 2:V
        const bool do_elu = matrix < 2;
        u16* out = (u16*)Cv + (size_t)matrix * 8388608;
        const int c0 = (by & 3) * 256 + wn*64 + li;
        #pragma unroll
        for (int m = 0; m < 4; ++m)
            #pragma unroll
            for (int n = 0; n < 4; ++n)
                #pragma unroll
                for (int r = 0; r < 4; ++r) {
                    float v = acc[m][n][r];
                    if (do_elu) v = elu1(v);
                    out[(size_t)(r0 + m*16 + r) * 1024 + c0 + n*16] = f2bf(v);
                }
    } else {
        float* out = (float*)Cv;
        const int c0 = n0 + wn*64 + li;
        #pragma unroll
        for (int m = 0; m < 4; ++m)
            #pragma unroll
            for (int n = 0; n < 4; ++n)
                #pragma unroll
                for (int r = 0; r < 4; ++r)
                    out[(size_t)(r0 + m*16 + r) * 1024 + c0 + n*16] = acc[m][n][r];
    }
}

// ---------------- per-chunk KV sums (bf16 in, fp32 out, TRANSPOSED [e][d]) ----------------
__global__ __launch_bounds__(256) void k_chunksums(
    const u16* __restrict__ Kg, const u16* __restrict__ Vg,
    float* __restrict__ CKVt, float* __restrict__ CKS)
{
    const int tid = threadIdx.x;
    const int tx = tid & 15, ty = tid >> 4;
    const int c  = blockIdx.x & 63;
    const int bh = blockIdx.x >> 6;
    const int b = bh >> 4, h = bh & 15;
    const int row0 = b * 4096 + c * 64;
    const int col  = h * 64;

    __shared__ float Ks[64][68];
    __shared__ float Vs[64][68];

    #pragma unroll
    for (int r = 0; r < 2; ++r) {
        int idx = tid + r * 256;
        int i = idx >> 3, cg = (idx & 7) << 3;
        uint4 ku = *(const uint4*)&Kg[(size_t)(row0 + i) * 1024 + col + cg];
        uint4 vu = *(const uint4*)&Vg[(size_t)(row0 + i) * 1024 + col + cg];
        Ks[i][cg+0]=bflo(ku.x); Ks[i][cg+1]=bfhi(ku.x);
        Ks[i][cg+2]=bflo(ku.y); Ks[i][cg+3]=bfhi(ku.y);
        Ks[i][cg+4]=bflo(ku.z); Ks[i][cg+5]=bfhi(ku.z);
        Ks[i][cg+6]=bflo(ku.w); Ks[i][cg+7]=bfhi(ku.w);
        Vs[i][cg+0]=bflo(vu.x); Vs[i][cg+1]=bfhi(vu.x);
        Vs[i][cg+2]=bflo(vu.y); Vs[i][cg+3]=bfhi(vu.y);
        Vs[i][cg+4]=bflo(vu.z); Vs[i][cg+5]=bfhi(vu.z);
        Vs[i][cg+6]=bflo(vu.w); Vs[i][cg+7]=bfhi(vu.w);
    }
    __syncthreads();

    float acc[4][4] = {};
    #pragma unroll 8
    for (int i = 0; i < 64; ++i) {
        float kv[4], vv[4];
        f4a(*(const float4*)&Ks[i][ty*4], kv);
        f4a(*(const float4*)&Vs[i][tx*4], vv);
        #pragma unroll
        for (int a = 0; a < 4; ++a)
            #pragma unroll
            for (int e = 0; e < 4; ++e)
                acc[a][e] = fmaf(kv[a], vv[e], acc[a][e]);
    }
    float* ckv = &CKVt[(size_t)blockIdx.x * 4096];
    #pragma unroll
    for (int e = 0; e < 4; ++e)
        *(float4*)&ckv[(tx*4 + e) * 64 + ty*4] =
            make_float4(acc[0][e], acc[1][e], acc[2][e], acc[3][e]);

    if (tid < 64) {
        float s = 0.f;
        #pragma unroll 8
        for (int i = 0; i < 64; ++i) s += Ks[i][tid];
        CKS[(size_t)blockIdx.x * 64 + tid] = s;
    }
}

// ---------------- exclusive prefix over chunks: fp32 in -> bf16 out ----------------
__global__ __launch_bounds__(256) void k_prefix_kv(
    const float* __restrict__ CKVt, u16* __restrict__ CKVp)
{
    const int bh = blockIdx.x >> 4;
    const int p  = ((blockIdx.x & 15) << 8) + threadIdx.x;
    const size_t base = (size_t)bh * 64 * 4096 + p;
    float acc = 0.f;
    #pragma unroll
    for (int c = 0; c < 64; ++c) {
        float t = CKVt[base + (size_t)c * 4096];
        CKVp[base + (size_t)c * 4096] = f2bf(acc);
        acc += t;
    }
}

__global__ __launch_bounds__(256) void k_prefix_ks(float* __restrict__ CKS)
{
    const int idx = blockIdx.x * 256 + threadIdx.x;
    const int bh = idx >> 6, d = idx & 63;
    const size_t base = (size_t)bh * 64 * 64 + d;
    float v[64];
    #pragma unroll
    for (int c = 0; c < 64; ++c) v[c] = CKS[base + (size_t)c * 64];
    float acc = 0.f;
    #pragma unroll
    for (int c = 0; c < 64; ++c) { float t = v[c]; CKS[base + (size_t)c * 64] = acc; acc += t; }
}

// ---------------- MFMA per-chunk attention ----------------
#define LSTR 72
__global__ __launch_bounds__(256) void k_attn2(
    const u16* __restrict__ Qg, const u16* __restrict__ Kg, const u16* __restrict__ Vg,
    const u16* __restrict__ Stg, const float* __restrict__ KSg, u16* __restrict__ AO)
{
    const int tid = threadIdx.x;
    const int l = tid & 63;
    const int w = tid >> 6;
    const int c  = blockIdx.x & 63;
    const int bh = blockIdx.x >> 6;
    const int row0 = (bh >> 4) * 4096 + c * 64;
    const int col  = (bh & 15) * 64;

    __shared__ __align__(16) u16 Qs [64 * LSTR];
    __shared__ __align__(16) u16 Ks [64 * LSTR];
    __shared__ __align__(16) u16 Vt [64 * LSTR];
    __shared__ __align__(16) u16 Sts[64 * LSTR];
    __shared__ __align__(16) u16 Pl [64 * LSTR];
    __shared__ float ksumF[64];
    __shared__ float invdenL[64];

    #pragma unroll
    for (int r = 0; r < 2; ++r) {
        int idx = tid + r * 256;
        int i = idx >> 3, cg = (idx & 7) << 3;
        *(uint4*)&Qs [i*LSTR + cg] = *(const uint4*)&Qg [(size_t)(row0 + i) * 1024 + col + cg];
        *(uint4*)&Ks [i*LSTR + cg] = *(const uint4*)&Kg [(size_t)(row0 + i) * 1024 + col + cg];
        *(uint4*)&Sts[i*LSTR + cg] = *(const uint4*)&Stg[(size_t)blockIdx.x * 4096 + i * 64 + cg];
        uint4 vu = *(const uint4*)&Vg[(size_t)(row0 + i) * 1024 + col + cg];
        Vt[(cg+0)*LSTR + i] = (u16)(vu.x & 0xffff);
        Vt[(cg+1)*LSTR + i] = (u16)(vu.x >> 16);
        Vt[(cg+2)*LSTR + i] = (u16)(vu.y & 0xffff);
        Vt[(cg+3)*LSTR + i] = (u16)(vu.y >> 16);
        Vt[(cg+4)*LSTR + i] = (u16)(vu.z & 0xffff);
        Vt[(cg+5)*LSTR + i] = (u16)(vu.z >> 16);
        Vt[(cg+6)*LSTR + i] = (u16)(vu.w & 0xffff);
        Vt[(cg+7)*LSTR + i] = (u16)(vu.w >> 16);
    }
    if (tid < 64) ksumF[tid] = KSg[(size_t)blockIdx.x * 64 + tid];
    __syncthreads();

    const int li = l & 15;
    const int lg = l >> 4;
    const int i_row = w * 16 + li;

    short8v bq[2];
    #pragma unroll
    for (int kc = 0; kc < 2; ++kc)
        bq[kc] = *(const short8v*)&Qs[i_row * LSTR + lg*8 + kc*32];

    float den = EPSF;
    #pragma unroll
    for (int mj = 0; mj < 4; ++mj) {
        f32x4 sacc = (f32x4){0.f, 0.f, 0.f, 0.f};
        #pragma unroll
        for (int kc = 0; kc < 2; ++kc) {
            short8v ak = *(const short8v*)&Ks[(mj*16 + li) * LSTR + lg*8 + kc*32];
            sacc = __builtin_amdgcn_mfma_f32_16x16x32_bf16(ak, bq[kc], sacc, 0, 0, 0);
        }
        const int jbase = mj*16 + lg*4;
        float pv[4];
        #pragma unroll
        for (int r = 0; r < 4; ++r) {
            float v = sacc[r];
            v = (jbase + r <= i_row) ? v : 0.f;
            den += v;
            pv[r] = v;
        }
        u32 lo = (u32)f2bf(pv[0]) | ((u32)f2bf(pv[1]) << 16);
        u32 hi = (u32)f2bf(pv[2]) | ((u32)f2bf(pv[3]) << 16);
        *(uint2*)&Pl[i_row * LSTR + jbase] = make_uint2(lo, hi);
    }

    {
        const int d0 = lg * 16;
        uint4 q1 = *(const uint4*)&Qs[i_row * LSTR + d0];
        uint4 q2 = *(const uint4*)&Qs[i_row * LSTR + d0 + 8];
        den += bflo(q1.x)*ksumF[d0+0] + bfhi(q1.x)*ksumF[d0+1]
             + bflo(q1.y)*ksumF[d0+2] + bfhi(q1.y)*ksumF[d0+3]
             + bflo(q1.z)*ksumF[d0+4] + bfhi(q1.z)*ksumF[d0+5]
             + bflo(q1.w)*ksumF[d0+6] + bfhi(q1.w)*ksumF[d0+7]
             + bflo(q2.x)*ksumF[d0+8] + bfhi(q2.x)*ksumF[d0+9]
             + bflo(q2.y)*ksumF[d0+10]+ bfhi(q2.y)*ksumF[d0+11]
             + bflo(q2.z)*ksumF[d0+12]+ bfhi(q2.z)*ksumF[d0+13]
             + bflo(q2.w)*ksumF[d0+14]+ bfhi(q2.w)*ksumF[d0+15];
    }
    den += __shfl_xor(den, 16);
    den += __shfl_xor(den, 32);
    if (l < 16) invdenL[w*16 + l] = 1.f / den;

    f32x4 oacc[4];
    #pragma unroll
    for (int ne = 0; ne < 4; ++ne) oacc[ne] = (f32x4){0.f, 0.f, 0.f, 0.f};
    #pragma unroll
    for (int kc = 0; kc < 2; ++kc) {
        short8v ap = *(const short8v*)&Pl[i_row * LSTR + lg*8 + kc*32];
        short8v aq = bq[kc];
        #pragma unroll
        for (int ne = 0; ne < 4; ++ne) {
            short8v bv = *(const short8v*)&Vt [(ne*16 + li) * LSTR + lg*8 + kc*32];
            short8v bs = *(const short8v*)&Sts[(ne*16 + li) * LSTR + lg*8 + kc*32];
            oacc[ne] = __builtin_amdgcn_mfma_f32_16x16x32_bf16(ap, bv, oacc[ne], 0, 0, 0);
            oacc[ne] = __builtin_amdgcn_mfma_f32_16x16x32_bf16(aq, bs, oacc[ne], 0, 0, 0);
        }
    }

    float inv[4];
    #pragma unroll
    for (int r = 0; r < 4; ++r) inv[r] = invdenL[w*16 + lg*4 + r];
    #pragma unroll
    for (int ne = 0; ne < 4; ++ne)
        #pragma unroll
        for (int r = 0; r < 4; ++r)
            Pl[(w*16 + lg*4 + r) * LSTR + ne*16 + li] = f2bf(oacc[ne][r] * inv[r]);

    #pragma unroll
    for (int p = 0; p < 2; ++p) {
        int idx2 = l + p * 64;
        int ro = w*16 + (idx2 >> 3), cg = (idx2 & 7) << 3;
        *(uint4*)&AO[(size_t)(row0 + ro) * 1024 + col + cg] = *(const uint4*)&Pl[ro*LSTR + cg];
    }
}

extern "C" void kernel_launch(void* const* d_in, const int* in_sizes, int n_in,
                              void* d_out, int out_size, void* d_ws, size_t ws_size,
                              hipStream_t stream)
{
    const float* x  = (const float*)d_in[0];
    const float* Wq = (const float*)d_in[1];
    const float* Wk = (const float*)d_in[2];
    const float* Wv = (const float*)d_in[3];
    const float* Wo = (const float*)d_in[4];
    float* out = (float*)d_out;

    char* w = (char*)d_ws;
    u16*   QKVb = (u16*)(w);                        // 3 x 16777216 B
    u16*   Qb   = QKVb;
    u16*   Kb   = QKVb + 8388608;
    u16*   Vb   = QKVb + 16777216;
    u16*   xb   = (u16*)(w + 50331648);             // 16777216 B (aliased AOb)
    u16*   AOb  = xb;
    u16*   Wcat = (u16*)(w + 67108864);             //  6291456 B
    u16*   Wob  = (u16*)(w + 73400320);             //  2097152 B
    float* CKV  = (float*)(w + 75497472);           // 33554432 B
    u16*   CKVp = (u16*)(w + 109051904);            // 16777216 B
    float* CKS  = (float*)(w + 125829120);          //   524288 B

    hipFuncSetAttribute(reinterpret_cast<const void*>(k_gemm5<1,12>),
                        hipFuncAttributeMaxDynamicSharedMemorySize, 98304);
    hipFuncSetAttribute(reinterpret_cast<const void*>(k_gemm5<3,4>),
                        hipFuncAttributeMaxDynamicSharedMemorySize, 98304);

    k_cast5      <<<6144, 256, 0, stream>>>(x, Wq, Wk, Wv, Wo, xb, Wcat, Wob);
    k_gemm5<1,12><<<768,  512, 98304, stream>>>(xb, Wcat, (void*)QKVb);
    k_chunksums  <<<2048, 256, 0, stream>>>(Kb, Vb, CKV, CKS);
    k_prefix_kv  <<<512,  256, 0, stream>>>(CKV, CKVp);
    k_prefix_ks  <<<8,    256, 0, stream>>>(CKS);
    k_attn2      <<<2048, 256, 0, stream>>>(Qb, Kb, Vb, CKVp, CKS, AOb);
    k_gemm5<3,4> <<<256,  512, 98304, stream>>>(AOb, Wob, (void*)out);
}

// Round 5
// 140.562 us; speedup vs baseline: 6.9930x; 1.0145x over previous
//
#include <hip/hip_runtime.h>
#include <math.h>

// LinearAttention: B=2, S=4096, D=1024, H=16, Dh=64
// Round 5: QKV GEMM -> k_gemm6: BM256xBN128, BK=32 dbuf, 4 waves, wave tile
// 128x64 (ratio 2.67 MFMA:ds_read), 3 blocks/CU (48KB LDS), grid 768 = 3x256
// balanced. T3-minimum schedule, zero-conflict slot swizzle. CKV chunk state
// stored bf16 (fp32 internal accum), in-place prefix. Out-GEMM/attn unchanged.

#define EPSF 1e-8f

typedef unsigned short u16;
typedef unsigned int   u32;
typedef __attribute__((ext_vector_type(8))) short short8v;
typedef __attribute__((ext_vector_type(4))) float f32x4;

__device__ __forceinline__ float elu1(float x){ return x > 0.f ? x + 1.f : __expf(x); }
__device__ __forceinline__ u16 f2bf(float f){
    union{float f; u32 i;} c; c.f = f;
    u32 i = c.i + 0x7FFFu + ((c.i >> 16) & 1u);   // RNE
    return (u16)(i >> 16);
}
__device__ __forceinline__ float bf2f(u16 v){ union{u32 i; float f;} c; c.i = (u32)v << 16; return c.f; }
__device__ __forceinline__ float bflo(u32 v){ union{u32 i; float f;} c; c.i = v << 16; return c.f; }
__device__ __forceinline__ float bfhi(u32 v){ union{u32 i; float f;} c; c.i = v & 0xffff0000u; return c.f; }
__device__ __forceinline__ void f4a(float4 v, float* a){ a[0]=v.x; a[1]=v.y; a[2]=v.z; a[3]=v.w; }

__device__ __forceinline__ void gload16(const void* g, void* l){
    __builtin_amdgcn_global_load_lds((const __attribute__((address_space(1))) u32*)g,
                                     (__attribute__((address_space(3))) u32*)l, 16, 0, 0);
}

// ---------------- Kernel 0: cast fp32 -> bf16 ----------------
__global__ __launch_bounds__(256) void k_cast5(
    const float* __restrict__ x,  const float* __restrict__ wq,
    const float* __restrict__ wk, const float* __restrict__ wv,
    const float* __restrict__ wo,
    u16* __restrict__ xb, u16* __restrict__ wcat, u16* __restrict__ wob)
{
    size_t i8 = ((size_t)blockIdx.x * 256 + threadIdx.x) * 8;
    const float* s; u16* d; size_t off;
    if      (i8 <  8388608) { s = x;  d = xb;            off = i8; }
    else if (i8 <  9437184) { s = wq; d = wcat;          off = i8 - 8388608; }
    else if (i8 < 10485760) { s = wk; d = wcat + 1048576; off = i8 - 9437184; }
    else if (i8 < 11534336) { s = wv; d = wcat + 2097152; off = i8 - 10485760; }
    else                    { s = wo; d = wob;           off = i8 - 11534336; }
    float4 a = *(const float4*)&s[off];
    float4 b = *(const float4*)&s[off + 4];
    uint4 p;
    p.x = (u32)f2bf(a.x) | ((u32)f2bf(a.y) << 16);
    p.y = (u32)f2bf(a.z) | ((u32)f2bf(a.w) << 16);
    p.z = (u32)f2bf(b.x) | ((u32)f2bf(b.y) << 16);
    p.w = (u32)f2bf(b.z) | ((u32)f2bf(b.w) << 16);
    *(uint4*)&d[off] = p;
}

// ---------------- k_gemm6: fused QKV GEMM-NT, 3-blocks/CU pipelined ----------------
// C[8192][3x1024] = A[8192][1024] * Wcat[3072][1024]^T.
// BM=256, BN=128, BK=32. 4 waves (2m x 1n... wm=wid>>1, wn=wid&1), wave tile 128x64,
// acc[8][4]. LDS 48KB static dbuf (A 16KB + B 8KB per buffer) -> 3 blocks/CU.
// Grid 768 = 3 rounds x 256 CUs exact. Per phase/wave: 12 ds_read_b128 -> 32 MFMA.
// Plane layout (zero-conflict, same scheme as r4): row-pairs per 128B line,
// 16B slot s = ((row&1)*4+kg) ^ (line&7); frag offsets = base + {m,n}*1024 (imm).
// Schedule (T3-minimum): top-of-iter stage(t+1)->buf[cur^1] (its last readers
// drained by the barrier ending iter t-1); ds_read+MFMA from buf[cur];
// vmcnt(0) -> barrier. One barrier per K-step, race-free.
__global__ __launch_bounds__(256, 3) void k_gemm6(
    const u16* __restrict__ Ag, const u16* __restrict__ Wg, u16* __restrict__ C)
{
    __shared__ __align__(16) char dsm[49152];
    const int bid = blockIdx.x;
    const int nid = (bid & 7) * 96 + (bid >> 3);   // XCD chunk swizzle, 768 = 8*96
    const int bx  = nid / 24;                      // m-tile 0..31
    const int by  = nid % 24;                      // n-tile 0..23 (into 3072)
    const int m0  = bx * 256;
    const int n0  = by * 128;                      // row into Wcat

    const int tid = threadIdx.x;
    const int l   = tid & 63;
    const int wid = tid >> 6;
    const int wm  = wid >> 1;      // 0..1 (m half)
    const int wn  = wid & 1;       // 0..1 (n half)
    const int li  = l & 15;
    const int kgi = l >> 4;

    // fragment read byte-offsets (within plane); +1024 per 16-row step
    const int ra0 = wm*128 + li;
    const int offA0 = (ra0 >> 1)*128 + (((((ra0 & 1) << 2) | kgi) ^ ((ra0 >> 1) & 7)) << 4);
    const int rb0 = wn*64 + li;
    const int offB0 = (rb0 >> 1)*128 + (((((rb0 & 1) << 2) | kgi) ^ ((rb0 >> 1) & 7)) << 4);

    // staging: linear LDS dest, inverse-swizzled global source.
    // lane handles linear slot q = j*256 + tid; line = q>>3 (line&7 == l>>3),
    // slot = l&7; source row = 2*(wid*8 + (l>>3)) + (sx>>2) + 64*j, kg = sx&3.
    const int sx   = (l & 7) ^ (l >> 3);
    const int rowb = 2*(wid*8 + (l >> 3)) + (sx >> 2);   // 0..63
    const int skg  = (sx & 3) * 8;
    const u16* srcA = Ag + (size_t)(m0 + rowb) * 1024 + skg;
    const u16* srcB = Wg + (size_t)(n0 + rowb) * 1024 + skg;

    f32x4 acc[8][4];
    #pragma unroll
    for (int m = 0; m < 8; ++m)
        #pragma unroll
        for (int n = 0; n < 4; ++n) acc[m][n] = (f32x4){0.f, 0.f, 0.f, 0.f};

    #define ST6(BUF, T) { \
        char* ab = dsm + (BUF)*24576; \
        char* bb = dsm + (BUF)*24576 + 16384; \
        _Pragma("unroll") for (int j = 0; j < 4; ++j) \
            gload16(srcA + (size_t)j*65536 + (T)*32, ab + j*4096 + wid*1024); \
        _Pragma("unroll") for (int j = 0; j < 2; ++j) \
            gload16(srcB + (size_t)j*65536 + (T)*32, bb + j*4096 + wid*1024); }

    ST6(0, 0);
    asm volatile("s_waitcnt vmcnt(0)" ::: "memory");
    __builtin_amdgcn_s_barrier();

    #pragma unroll 1
    for (int t = 0; t < 32; ++t) {
        const int cur = t & 1;
        if (t < 31) ST6(cur ^ 1, t + 1);
        const char* Ab = dsm + cur*24576;
        const char* Bb = dsm + cur*24576 + 16384;
        short8v bfr[4];
        #pragma unroll
        for (int n = 0; n < 4; ++n) bfr[n] = *(const short8v*)(Bb + offB0 + n*1024);
        __builtin_amdgcn_s_setprio(1);
        #pragma unroll
        for (int m = 0; m < 8; ++m) {
            short8v afr = *(const short8v*)(Ab + offA0 + m*1024);
            #pragma unroll
            for (int n = 0; n < 4; ++n)
                acc[m][n] = __builtin_amdgcn_mfma_f32_16x16x32_bf16(afr, bfr[n], acc[m][n], 0, 0, 0);
        }
        __builtin_amdgcn_s_setprio(0);
        asm volatile("s_waitcnt vmcnt(0)" ::: "memory");
        __builtin_amdgcn_s_barrier();
    }
    #undef ST6

    // epilogue. C/D layout: col = lane&15, row = (lane>>4)*4 + reg
    const int matrix = by >> 3;                 // 0:Q 1:K 2:V
    const bool do_elu = matrix < 2;
    u16* outp = C + (size_t)matrix * 8388608;
    const int r0 = m0 + wm*128 + kgi*4;
    const int c0 = (by & 7)*128 + wn*64 + li;
    #pragma unroll
    for (int m = 0; m < 8; ++m)
        #pragma unroll
        for (int n = 0; n < 4; ++n)
            #pragma unroll
            for (int r = 0; r < 4; ++r) {
                float v = acc[m][n][r];
                if (do_elu) v = elu1(v);
                outp[(size_t)(r0 + m*16 + r) * 1024 + c0 + n*16] = f2bf(v);
            }
}

// ---------------- out GEMM: r4 pipelined template (BM128xBN256, 8 waves) ----------------
#define AOFF(BUF,KH) ((BUF)*49152 + (KH)*8192)
#define BOFF(BUF,KH) ((BUF)*49152 + 16384 + (KH)*16384)

#define ST(BUF, KT, KH) { \
    gload16(Ag + (size_t)(m0 + sRow)*1024 + (KT)*64 + (KH)*32 + sKg, dsm + AOFF(BUF,KH) + wvv*1024); \
    gload16(Wg + (size_t)(n0 + sRow)*1024 + (KT)*64 + (KH)*32 + sKg, dsm + BOFF(BUF,KH) + wvv*1024); \
    gload16(Wg + (size_t)(n0 + 128 + sRow)*1024 + (KT)*64 + (KH)*32 + sKg, dsm + BOFF(BUF,KH) + 8192 + wvv*1024); }

#define PH(BUF, KH, STCODE, CNT) { \
    short8v a[4], b[4]; \
    const char* Ab = dsm + AOFF(BUF,KH); \
    const char* Bb = dsm + BOFF(BUF,KH); \
    _Pragma("unroll") for (int m = 0; m < 4; ++m) a[m] = *(const short8v*)(Ab + offA[m]); \
    _Pragma("unroll") for (int n = 0; n < 4; ++n) b[n] = *(const short8v*)(Bb + offB[n]); \
    STCODE; \
    __builtin_amdgcn_s_setprio(1); \
    _Pragma("unroll") for (int m = 0; m < 4; ++m) \
        _Pragma("unroll") for (int n = 0; n < 4; ++n) \
            acc[m][n] = __builtin_amdgcn_mfma_f32_16x16x32_bf16(a[m], b[n], acc[m][n], 0, 0, 0); \
    __builtin_amdgcn_s_setprio(0); \
    asm volatile("s_waitcnt vmcnt(" #CNT ")" ::: "memory"); \
    __builtin_amdgcn_s_barrier(); }

template<int NBY>
__global__ __launch_bounds__(512, 2) void k_gemm5(
    const u16* __restrict__ Ag, const u16* __restrict__ Wg, float* __restrict__ Cv)
{
    extern __shared__ char dsm[];
    const int nid = (blockIdx.x & 7) * ((64 * NBY) >> 3) + (blockIdx.x >> 3);
    const int bx  = nid / NBY;
    const int by  = nid % NBY;
    const int m0  = bx * 128;
    const int n0  = by * 256;

    const int tid = threadIdx.x;
    const int l   = tid & 63;
    const int wid = tid >> 6;
    const int wm  = wid >> 2;
    const int wn  = wid & 3;
    const int li  = l & 15;
    const int kgi = l >> 4;

    int offA[4], offB[4];
    #pragma unroll
    for (int m = 0; m < 4; ++m) {
        int ra = wm*64 + m*16 + li;
        offA[m] = (ra >> 1)*128 + (((((ra & 1) << 2) | kgi) ^ ((ra >> 1) & 7)) << 4);
        int rb = wn*64 + m*16 + li;
        offB[m] = (rb >> 1)*128 + (((((rb & 1) << 2) | kgi) ^ ((rb >> 1) & 7)) << 4);
    }
    const int wvv  = wid;
    const int sx   = (l & 7) ^ (l >> 3);
    const int sRow = 2*(wvv*8 + (l >> 3)) + (sx >> 2);
    const int sKg  = (sx & 3) * 8;

    f32x4 acc[4][4];
    #pragma unroll
    for (int m = 0; m < 4; ++m)
        #pragma unroll
        for (int n = 0; n < 4; ++n) acc[m][n] = (f32x4){0.f, 0.f, 0.f, 0.f};

    ST(0, 0, 0); ST(0, 0, 1); ST(1, 1, 0);
    asm volatile("s_waitcnt vmcnt(6)" ::: "memory");
    __builtin_amdgcn_s_barrier();

    #pragma unroll 1
    for (int it = 0; it < 7; ++it) {
        const int T = it * 2;
        PH(0, 0, ST(1, T+1, 1), 6);
        PH(0, 1, ST(0, T+2, 0), 6);
        PH(1, 0, ST(0, T+2, 1), 6);
        PH(1, 1, ST(1, T+3, 0), 6);
    }
    PH(0, 0, ST(1, 15, 1), 6);
    PH(0, 1, {}, 3);
    PH(1, 0, {}, 0);
    {
        short8v a[4], b[4];
        const char* Ab = dsm + AOFF(1,1);
        const char* Bb = dsm + BOFF(1,1);
        #pragma unroll
        for (int m = 0; m < 4; ++m) a[m] = *(const short8v*)(Ab + offA[m]);
        #pragma unroll
        for (int n = 0; n < 4; ++n) b[n] = *(const short8v*)(Bb + offB[n]);
        #pragma unroll
        for (int m = 0; m < 4; ++m)
            #pragma unroll
            for (int n = 0; n < 4; ++n)
                acc[m][n] = __builtin_amdgcn_mfma_f32_16x16x32_bf16(a[m], b[n], acc[m][n], 0, 0, 0);
    }

    const int r0 = m0 + wm*64 + (l >> 4) * 4;
    const int c0 = n0 + wn*64 + li;
    #pragma unroll
    for (int m = 0; m < 4; ++m)
        #pragma unroll
        for (int n = 0; n < 4; ++n)
            #pragma unroll
            for (int r = 0; r < 4; ++r)
                Cv[(size_t)(r0 + m*16 + r) * 1024 + c0 + n*16] = acc[m][n][r];
}

// ---------------- per-chunk KV sums (bf16 in, bf16 out [e][d], fp32 accum) ----------------
__global__ __launch_bounds__(256) void k_chunksums(
    const u16* __restrict__ Kg, const u16* __restrict__ Vg,
    u16* __restrict__ CKVb, float* __restrict__ CKS)
{
    const int tid = threadIdx.x;
    const int tx = tid & 15, ty = tid >> 4;
    const int c  = blockIdx.x & 63;
    const int bh = blockIdx.x >> 6;
    const int b = bh >> 4, h = bh & 15;
    const int row0 = b * 4096 + c * 64;
    const int col  = h * 64;

    __shared__ float Ks[64][68];
    __shared__ float Vs[64][68];

    #pragma unroll
    for (int r = 0; r < 2; ++r) {
        int idx = tid + r * 256;
        int i = idx >> 3, cg = (idx & 7) << 3;
        uint4 ku = *(const uint4*)&Kg[(size_t)(row0 + i) * 1024 + col + cg];
        uint4 vu = *(const uint4*)&Vg[(size_t)(row0 + i) * 1024 + col + cg];
        Ks[i][cg+0]=bflo(ku.x); Ks[i][cg+1]=bfhi(ku.x);
        Ks[i][cg+2]=bflo(ku.y); Ks[i][cg+3]=bfhi(ku.y);
        Ks[i][cg+4]=bflo(ku.z); Ks[i][cg+5]=bfhi(ku.z);
        Ks[i][cg+6]=bflo(ku.w); Ks[i][cg+7]=bfhi(ku.w);
        Vs[i][cg+0]=bflo(vu.x); Vs[i][cg+1]=bfhi(vu.x);
        Vs[i][cg+2]=bflo(vu.y); Vs[i][cg+3]=bfhi(vu.y);
        Vs[i][cg+4]=bflo(vu.z); Vs[i][cg+5]=bfhi(vu.z);
        Vs[i][cg+6]=bflo(vu.w); Vs[i][cg+7]=bfhi(vu.w);
    }
    __syncthreads();

    float acc[4][4] = {};   // acc[a=d-sub][e-sub]
    #pragma unroll 8
    for (int i = 0; i < 64; ++i) {
        float kv[4], vv[4];
        f4a(*(const float4*)&Ks[i][ty*4], kv);
        f4a(*(const float4*)&Vs[i][tx*4], vv);
        #pragma unroll
        for (int a = 0; a < 4; ++a)
            #pragma unroll
            for (int e = 0; e < 4; ++e)
                acc[a][e] = fmaf(kv[a], vv[e], acc[a][e]);
    }
    // transposed write: CKVb[e][d] bf16
    u16* ckv = &CKVb[(size_t)blockIdx.x * 4096];
    #pragma unroll
    for (int e = 0; e < 4; ++e) {
        u32 p0 = (u32)f2bf(acc[0][e]) | ((u32)f2bf(acc[1][e]) << 16);
        u32 p1 = (u32)f2bf(acc[2][e]) | ((u32)f2bf(acc[3][e]) << 16);
        *(uint2*)&ckv[(tx*4 + e) * 64 + ty*4] = make_uint2(p0, p1);
    }

    if (tid < 64) {
        float s = 0.f;
        #pragma unroll 8
        for (int i = 0; i < 64; ++i) s += Ks[i][tid];
        CKS[(size_t)blockIdx.x * 64 + tid] = s;
    }
}

// ---------------- exclusive prefix over chunks: in-place bf16, fp32 accum ----------------
__global__ __launch_bounds__(256) void k_prefix_kv(u16* __restrict__ CKV)
{
    const int bh = blockIdx.x >> 4;
    const int p  = ((blockIdx.x & 15) << 8) + threadIdx.x;
    const size_t base = (size_t)bh * 64 * 4096 + p;
    float acc = 0.f;
    #pragma unroll
    for (int c = 0; c < 64; ++c) {
        float t = bf2f(CKV[base + (size_t)c * 4096]);
        CKV[base + (size_t)c * 4096] = f2bf(acc);
        acc += t;
    }
}

__global__ __launch_bounds__(256) void k_prefix_ks(float* __restrict__ CKS)
{
    const int idx = blockIdx.x * 256 + threadIdx.x;
    const int bh = idx >> 6, d = idx & 63;
    const size_t base = (size_t)bh * 64 * 64 + d;
    float v[64];
    #pragma unroll
    for (int c = 0; c < 64; ++c) v[c] = CKS[base + (size_t)c * 64];
    float acc = 0.f;
    #pragma unroll
    for (int c = 0; c < 64; ++c) { float t = v[c]; CKS[base + (size_t)c * 64] = acc; acc += t; }
}

// ---------------- MFMA per-chunk attention ----------------
#define LSTR 72
__global__ __launch_bounds__(256) void k_attn2(
    const u16* __restrict__ Qg, const u16* __restrict__ Kg, const u16* __restrict__ Vg,
    const u16* __restrict__ Stg, const float* __restrict__ KSg, u16* __restrict__ AO)
{
    const int tid = threadIdx.x;
    const int l = tid & 63;
    const int w = tid >> 6;
    const int c  = blockIdx.x & 63;
    const int bh = blockIdx.x >> 6;
    const int row0 = (bh >> 4) * 4096 + c * 64;
    const int col  = (bh & 15) * 64;

    __shared__ __align__(16) u16 Qs [64 * LSTR];
    __shared__ __align__(16) u16 Ks [64 * LSTR];
    __shared__ __align__(16) u16 Vt [64 * LSTR];
    __shared__ __align__(16) u16 Sts[64 * LSTR];
    __shared__ __align__(16) u16 Pl [64 * LSTR];
    __shared__ float ksumF[64];
    __shared__ float invdenL[64];

    #pragma unroll
    for (int r = 0; r < 2; ++r) {
        int idx = tid + r * 256;
        int i = idx >> 3, cg = (idx & 7) << 3;
        *(uint4*)&Qs [i*LSTR + cg] = *(const uint4*)&Qg [(size_t)(row0 + i) * 1024 + col + cg];
        *(uint4*)&Ks [i*LSTR + cg] = *(const uint4*)&Kg [(size_t)(row0 + i) * 1024 + col + cg];
        *(uint4*)&Sts[i*LSTR + cg] = *(const uint4*)&Stg[(size_t)blockIdx.x * 4096 + i * 64 + cg];
        uint4 vu = *(const uint4*)&Vg[(size_t)(row0 + i) * 1024 + col + cg];
        Vt[(cg+0)*LSTR + i] = (u16)(vu.x & 0xffff);
        Vt[(cg+1)*LSTR + i] = (u16)(vu.x >> 16);
        Vt[(cg+2)*LSTR + i] = (u16)(vu.y & 0xffff);
        Vt[(cg+3)*LSTR + i] = (u16)(vu.y >> 16);
        Vt[(cg+4)*LSTR + i] = (u16)(vu.z & 0xffff);
        Vt[(cg+5)*LSTR + i] = (u16)(vu.z >> 16);
        Vt[(cg+6)*LSTR + i] = (u16)(vu.w & 0xffff);
        Vt[(cg+7)*LSTR + i] = (u16)(vu.w >> 16);
    }
    if (tid < 64) ksumF[tid] = KSg[(size_t)blockIdx.x * 64 + tid];
    __syncthreads();

    const int li = l & 15;
    const int lg = l >> 4;
    const int i_row = w * 16 + li;

    short8v bq[2];
    #pragma unroll
    for (int kc = 0; kc < 2; ++kc)
        bq[kc] = *(const short8v*)&Qs[i_row * LSTR + lg*8 + kc*32];

    float den = EPSF;
    #pragma unroll
    for (int mj = 0; mj < 4; ++mj) {
        f32x4 sacc = (f32x4){0.f, 0.f, 0.f, 0.f};
        #pragma unroll
        for (int kc = 0; kc < 2; ++kc) {
            short8v ak = *(const short8v*)&Ks[(mj*16 + li) * LSTR + lg*8 + kc*32];
            sacc = __builtin_amdgcn_mfma_f32_16x16x32_bf16(ak, bq[kc], sacc, 0, 0, 0);
        }
        const int jbase = mj*16 + lg*4;
        float pv[4];
        #pragma unroll
        for (int r = 0; r < 4; ++r) {
            float v = sacc[r];
            v = (jbase + r <= i_row) ? v : 0.f;
            den += v;
            pv[r] = v;
        }
        u32 lo = (u32)f2bf(pv[0]) | ((u32)f2bf(pv[1]) << 16);
        u32 hi = (u32)f2bf(pv[2]) | ((u32)f2bf(pv[3]) << 16);
        *(uint2*)&Pl[i_row * LSTR + jbase] = make_uint2(lo, hi);
    }

    {
        const int d0 = lg * 16;
        uint4 q1 = *(const uint4*)&Qs[i_row * LSTR + d0];
        uint4 q2 = *(const uint4*)&Qs[i_row * LSTR + d0 + 8];
        den += bflo(q1.x)*ksumF[d0+0] + bfhi(q1.x)*ksumF[d0+1]
             + bflo(q1.y)*ksumF[d0+2] + bfhi(q1.y)*ksumF[d0+3]
             + bflo(q1.z)*ksumF[d0+4] + bfhi(q1.z)*ksumF[d0+5]
             + bflo(q1.w)*ksumF[d0+6] + bfhi(q1.w)*ksumF[d0+7]
             + bflo(q2.x)*ksumF[d0+8] + bfhi(q2.x)*ksumF[d0+9]
             + bflo(q2.y)*ksumF[d0+10]+ bfhi(q2.y)*ksumF[d0+11]
             + bflo(q2.z)*ksumF[d0+12]+ bfhi(q2.z)*ksumF[d0+13]
             + bflo(q2.w)*ksumF[d0+14]+ bfhi(q2.w)*ksumF[d0+15];
    }
    den += __shfl_xor(den, 16);
    den += __shfl_xor(den, 32);
    if (l < 16) invdenL[w*16 + l] = 1.f / den;

    f32x4 oacc[4];
    #pragma unroll
    for (int ne = 0; ne < 4; ++ne) oacc[ne] = (f32x4){0.f, 0.f, 0.f, 0.f};
    #pragma unroll
    for (int kc = 0; kc < 2; ++kc) {
        short8v ap = *(const short8v*)&Pl[i_row * LSTR + lg*8 + kc*32];
        short8v aq = bq[kc];
        #pragma unroll
        for (int ne = 0; ne < 4; ++ne) {
            short8v bv = *(const short8v*)&Vt [(ne*16 + li) * LSTR + lg*8 + kc*32];
            short8v bs = *(const short8v*)&Sts[(ne*16 + li) * LSTR + lg*8 + kc*32];
            oacc[ne] = __builtin_amdgcn_mfma_f32_16x16x32_bf16(ap, bv, oacc[ne], 0, 0, 0);
            oacc[ne] = __builtin_amdgcn_mfma_f32_16x16x32_bf16(aq, bs, oacc[ne], 0, 0, 0);
        }
    }

    float inv[4];
    #pragma unroll
    for (int r = 0; r < 4; ++r) inv[r] = invdenL[w*16 + lg*4 + r];
    #pragma unroll
    for (int ne = 0; ne < 4; ++ne)
        #pragma unroll
        for (int r = 0; r < 4; ++r)
            Pl[(w*16 + lg*4 + r) * LSTR + ne*16 + li] = f2bf(oacc[ne][r] * inv[r]);

    #pragma unroll
    for (int p = 0; p < 2; ++p) {
        int idx2 = l + p * 64;
        int ro = w*16 + (idx2 >> 3), cg = (idx2 & 7) << 3;
        *(uint4*)&AO[(size_t)(row0 + ro) * 1024 + col + cg] = *(const uint4*)&Pl[ro*LSTR + cg];
    }
}

extern "C" void kernel_launch(void* const* d_in, const int* in_sizes, int n_in,
                              void* d_out, int out_size, void* d_ws, size_t ws_size,
                              hipStream_t stream)
{
    const float* x  = (const float*)d_in[0];
    const float* Wq = (const float*)d_in[1];
    const float* Wk = (const float*)d_in[2];
    const float* Wv = (const float*)d_in[3];
    const float* Wo = (const float*)d_in[4];
    float* out = (float*)d_out;

    char* w = (char*)d_ws;
    u16*   QKVb = (u16*)(w);                        // 3 x 16777216 B = 50331648
    u16*   Qb   = QKVb;
    u16*   Kb   = QKVb + 8388608;
    u16*   Vb   = QKVb + 16777216;
    u16*   xb   = (u16*)(w + 50331648);             // 16777216 B (aliased AOb)
    u16*   AOb  = xb;
    u16*   Wcat = (u16*)(w + 67108864);             //  6291456 B
    u16*   Wob  = (u16*)(w + 73400320);             //  2097152 B
    u16*   CKVb = (u16*)(w + 75497472);             // 16777216 B (bf16, prefix in-place)
    float* CKS  = (float*)(w + 92274688);           //   524288 B  -> end 92798976

    hipFuncSetAttribute(reinterpret_cast<const void*>(k_gemm5<4>),
                        hipFuncAttributeMaxDynamicSharedMemorySize, 98304);

    k_cast5    <<<6144, 256, 0, stream>>>(x, Wq, Wk, Wv, Wo, xb, Wcat, Wob);
    k_gemm6    <<<768,  256, 0, stream>>>(xb, Wcat, QKVb);
    k_chunksums<<<2048, 256, 0, stream>>>(Kb, Vb, CKVb, CKS);
    k_prefix_kv<<<512,  256, 0, stream>>>(CKVb);
    k_prefix_ks<<<8,    256, 0, stream>>>(CKS);
    k_attn2    <<<2048, 256, 0, stream>>>(Qb, Kb, Vb, CKVb, CKS, AOb);
    k_gemm5<4> <<<256,  512, 98304, stream>>>(AOb, Wob, out);
}

// Round 6
// 140.403 us; speedup vs baseline: 7.0009x; 1.0011x over previous
//
#include <hip/hip_runtime.h>
#include <math.h>

// LinearAttention: B=2, S=4096, D=1024, H=16, Dh=64
// Round 6: k_gemm7 = BM256xBN128 BK32, 4 waves, acc[8][4], 3-buffer LDS ring
// (72KB) + counted vmcnt(6) never-drain (T4). Runway: stage(t+2) issued at
// iter t, consumed at iter t+2 (~2 iters > HBM latency). 2 blocks/CU
// (register-limited anyway: 84 VGPR + 128 AGPR). Used for QKV and out GEMMs.
// prefix_ks merged into prefix_kv. Attention chain otherwise unchanged.

#define EPSF 1e-8f

typedef unsigned short u16;
typedef unsigned int   u32;
typedef __attribute__((ext_vector_type(8))) short short8v;
typedef __attribute__((ext_vector_type(4))) float f32x4;

__device__ __forceinline__ float elu1(float x){ return x > 0.f ? x + 1.f : __expf(x); }
__device__ __forceinline__ u16 f2bf(float f){
    union{float f; u32 i;} c; c.f = f;
    u32 i = c.i + 0x7FFFu + ((c.i >> 16) & 1u);   // RNE
    return (u16)(i >> 16);
}
__device__ __forceinline__ float bf2f(u16 v){ union{u32 i; float f;} c; c.i = (u32)v << 16; return c.f; }
__device__ __forceinline__ float bflo(u32 v){ union{u32 i; float f;} c; c.i = v << 16; return c.f; }
__device__ __forceinline__ float bfhi(u32 v){ union{u32 i; float f;} c; c.i = v & 0xffff0000u; return c.f; }
__device__ __forceinline__ void f4a(float4 v, float* a){ a[0]=v.x; a[1]=v.y; a[2]=v.z; a[3]=v.w; }

__device__ __forceinline__ void gload16(const void* g, void* l){
    __builtin_amdgcn_global_load_lds((const __attribute__((address_space(1))) u32*)g,
                                     (__attribute__((address_space(3))) u32*)l, 16, 0, 0);
}

// ---------------- Kernel 0: cast fp32 -> bf16 ----------------
__global__ __launch_bounds__(256) void k_cast5(
    const float* __restrict__ x,  const float* __restrict__ wq,
    const float* __restrict__ wk, const float* __restrict__ wv,
    const float* __restrict__ wo,
    u16* __restrict__ xb, u16* __restrict__ wcat, u16* __restrict__ wob)
{
    size_t i8 = ((size_t)blockIdx.x * 256 + threadIdx.x) * 8;
    const float* s; u16* d; size_t off;
    if      (i8 <  8388608) { s = x;  d = xb;            off = i8; }
    else if (i8 <  9437184) { s = wq; d = wcat;          off = i8 - 8388608; }
    else if (i8 < 10485760) { s = wk; d = wcat + 1048576; off = i8 - 9437184; }
    else if (i8 < 11534336) { s = wv; d = wcat + 2097152; off = i8 - 10485760; }
    else                    { s = wo; d = wob;           off = i8 - 11534336; }
    float4 a = *(const float4*)&s[off];
    float4 b = *(const float4*)&s[off + 4];
    uint4 p;
    p.x = (u32)f2bf(a.x) | ((u32)f2bf(a.y) << 16);
    p.y = (u32)f2bf(a.z) | ((u32)f2bf(a.w) << 16);
    p.z = (u32)f2bf(b.x) | ((u32)f2bf(b.y) << 16);
    p.w = (u32)f2bf(b.z) | ((u32)f2bf(b.w) << 16);
    *(uint4*)&d[off] = p;
}

// ---------------- k_gemm7: GEMM-NT, 3-buffer ring + counted vmcnt ----------------
// C[8192][...] = A[8192][1024] * W[NBY*128][1024]^T. BM=256, BN=128, BK=32.
// 4 waves, wave tile 128x64, acc[8][4]. LDS ring: 3 bufs x (A 16KB + B 8KB).
// Iter t: stage(t+2)->buf[(t+2)%3]; compute buf[t%3]; vmcnt(6) (newest 6 =
// stage t+2 in flight, stage t+1 guaranteed landed); s_barrier.
// Clobber audit: stage(t+2) overwrites buf[(t-1)%3]; its readers (iter t-1 MFMAs)
// drained their ds_reads (compiler lgkmcnt before MFMA) before the barrier that
// precedes this ST -> race-free with one barrier/iter. No vmcnt(0) in main loop.
// Swizzle (verified 0-conflict in r4/r5): 16B slot s = ((row&1)*4+kg)^(line&7)
// within 128B row-pair lines; staging pre-swizzles the GLOBAL source address.
// MODE 1: QKV fused (bf16 out, elu on matrices 0,1; NBY=24). MODE 3: f32 out (NBY=8).
template<int MODE, int NBY>
__global__ __launch_bounds__(256, 2) void k_gemm7(
    const u16* __restrict__ Ag, const u16* __restrict__ Wg, void* __restrict__ Cv)
{
    __shared__ __align__(16) char dsm[73728];
    const int bid = blockIdx.x;
    const int nid = (bid & 7) * ((32 * NBY) >> 3) + (bid >> 3);   // XCD chunk swizzle
    const int bx  = nid / NBY;
    const int by  = nid % NBY;
    const int m0  = bx * 256;
    const int n0  = by * 128;

    const int tid = threadIdx.x;
    const int l   = tid & 63;
    const int wid = tid >> 6;
    const int wm  = wid >> 1;      // 0..1
    const int wn  = wid & 1;       // 0..1
    const int li  = l & 15;
    const int kgi = l >> 4;

    const int ra0 = wm*128 + li;
    const int offA0 = (ra0 >> 1)*128 + (((((ra0 & 1) << 2) | kgi) ^ ((ra0 >> 1) & 7)) << 4);
    const int rb0 = wn*64 + li;
    const int offB0 = (rb0 >> 1)*128 + (((((rb0 & 1) << 2) | kgi) ^ ((rb0 >> 1) & 7)) << 4);

    const int sx   = (l & 7) ^ (l >> 3);
    const int rowb = 2*(wid*8 + (l >> 3)) + (sx >> 2);   // 0..63
    const int skg  = (sx & 3) * 8;
    const u16* srcA = Ag + (size_t)(m0 + rowb) * 1024 + skg;
    const u16* srcB = Wg + (size_t)(n0 + rowb) * 1024 + skg;

    f32x4 acc[8][4];
    #pragma unroll
    for (int m = 0; m < 8; ++m)
        #pragma unroll
        for (int n = 0; n < 4; ++n) acc[m][n] = (f32x4){0.f, 0.f, 0.f, 0.f};

    #define ST7(BUF, T) { \
        char* ab = dsm + (BUF)*24576; \
        char* bb = ab + 16384; \
        _Pragma("unroll") for (int j = 0; j < 4; ++j) \
            gload16(srcA + (size_t)j*65536 + (T)*32, ab + j*4096 + wid*1024); \
        _Pragma("unroll") for (int j = 0; j < 2; ++j) \
            gload16(srcB + (size_t)j*65536 + (T)*32, bb + j*4096 + wid*1024); }

    #define CP7(BUF) { \
        const char* Ab = dsm + (BUF)*24576; \
        const char* Bb = Ab + 16384; \
        short8v bfr[4]; \
        _Pragma("unroll") for (int n = 0; n < 4; ++n) bfr[n] = *(const short8v*)(Bb + offB0 + n*1024); \
        __builtin_amdgcn_s_setprio(1); \
        _Pragma("unroll") for (int m = 0; m < 8; ++m) { \
            short8v afr = *(const short8v*)(Ab + offA0 + m*1024); \
            _Pragma("unroll") for (int n = 0; n < 4; ++n) \
                acc[m][n] = __builtin_amdgcn_mfma_f32_16x16x32_bf16(afr, bfr[n], acc[m][n], 0, 0, 0); \
        } \
        __builtin_amdgcn_s_setprio(0); }

    #define STEP7(CUR, STB, TS) { \
        ST7(STB, TS); \
        CP7(CUR); \
        asm volatile("s_waitcnt vmcnt(6)" ::: "memory"); \
        __builtin_amdgcn_s_barrier(); }

    // prologue: stage tiles 0,1; wait for tile 0 (newest 6 = tile 1 in flight)
    ST7(0, 0); ST7(1, 1);
    asm volatile("s_waitcnt vmcnt(6)" ::: "memory");
    __builtin_amdgcn_s_barrier();

    #pragma unroll 1
    for (int g = 0; g < 10; ++g) {          // iters 0..29
        const int t = g * 3;
        STEP7(0, 2, t + 2);
        STEP7(1, 0, t + 3);
        STEP7(2, 1, t + 4);
    }
    // iter 30: compute buf0; need stage(31) landed before iter 31
    CP7(0);
    asm volatile("s_waitcnt vmcnt(0)" ::: "memory");
    __builtin_amdgcn_s_barrier();
    // iter 31: compute buf1
    CP7(1);
    #undef STEP7
    #undef CP7
    #undef ST7

    // epilogue. C/D layout: col = lane&15, row = (lane>>4)*4 + reg
    const int r0 = m0 + wm*128 + kgi*4;
    if (MODE == 1) {
        const int matrix = by >> 3;                 // 0:Q 1:K 2:V
        const bool do_elu = matrix < 2;
        u16* outp = (u16*)Cv + (size_t)matrix * 8388608;
        const int c0 = (by & 7)*128 + wn*64 + li;
        #pragma unroll
        for (int m = 0; m < 8; ++m)
            #pragma unroll
            for (int n = 0; n < 4; ++n)
                #pragma unroll
                for (int r = 0; r < 4; ++r) {
                    float v = acc[m][n][r];
                    if (do_elu) v = elu1(v);
                    outp[(size_t)(r0 + m*16 + r) * 1024 + c0 + n*16] = f2bf(v);
                }
    } else {
        float* outp = (float*)Cv;
        const int c0 = by*128 + wn*64 + li;
        #pragma unroll
        for (int m = 0; m < 8; ++m)
            #pragma unroll
            for (int n = 0; n < 4; ++n)
                #pragma unroll
                for (int r = 0; r < 4; ++r)
                    outp[(size_t)(r0 + m*16 + r) * 1024 + c0 + n*16] = acc[m][n][r];
    }
}

// ---------------- per-chunk KV sums (bf16 in, bf16 out [e][d], fp32 accum) ----------------
__global__ __launch_bounds__(256) void k_chunksums(
    const u16* __restrict__ Kg, const u16* __restrict__ Vg,
    u16* __restrict__ CKVb, float* __restrict__ CKS)
{
    const int tid = threadIdx.x;
    const int tx = tid & 15, ty = tid >> 4;
    const int c  = blockIdx.x & 63;
    const int bh = blockIdx.x >> 6;
    const int b = bh >> 4, h = bh & 15;
    const int row0 = b * 4096 + c * 64;
    const int col  = h * 64;

    __shared__ float Ks[64][68];
    __shared__ float Vs[64][68];

    #pragma unroll
    for (int r = 0; r < 2; ++r) {
        int idx = tid + r * 256;
        int i = idx >> 3, cg = (idx & 7) << 3;
        uint4 ku = *(const uint4*)&Kg[(size_t)(row0 + i) * 1024 + col + cg];
        uint4 vu = *(const uint4*)&Vg[(size_t)(row0 + i) * 1024 + col + cg];
        Ks[i][cg+0]=bflo(ku.x); Ks[i][cg+1]=bfhi(ku.x);
        Ks[i][cg+2]=bflo(ku.y); Ks[i][cg+3]=bfhi(ku.y);
        Ks[i][cg+4]=bflo(ku.z); Ks[i][cg+5]=bfhi(ku.z);
        Ks[i][cg+6]=bflo(ku.w); Ks[i][cg+7]=bfhi(ku.w);
        Vs[i][cg+0]=bflo(vu.x); Vs[i][cg+1]=bfhi(vu.x);
        Vs[i][cg+2]=bflo(vu.y); Vs[i][cg+3]=bfhi(vu.y);
        Vs[i][cg+4]=bflo(vu.z); Vs[i][cg+5]=bfhi(vu.z);
        Vs[i][cg+6]=bflo(vu.w); Vs[i][cg+7]=bfhi(vu.w);
    }
    __syncthreads();

    float acc[4][4] = {};   // acc[a=d-sub][e-sub]
    #pragma unroll 8
    for (int i = 0; i < 64; ++i) {
        float kv[4], vv[4];
        f4a(*(const float4*)&Ks[i][ty*4], kv);
        f4a(*(const float4*)&Vs[i][tx*4], vv);
        #pragma unroll
        for (int a = 0; a < 4; ++a)
            #pragma unroll
            for (int e = 0; e < 4; ++e)
                acc[a][e] = fmaf(kv[a], vv[e], acc[a][e]);
    }
    u16* ckv = &CKVb[(size_t)blockIdx.x * 4096];
    #pragma unroll
    for (int e = 0; e < 4; ++e) {
        u32 p0 = (u32)f2bf(acc[0][e]) | ((u32)f2bf(acc[1][e]) << 16);
        u32 p1 = (u32)f2bf(acc[2][e]) | ((u32)f2bf(acc[3][e]) << 16);
        *(uint2*)&ckv[(tx*4 + e) * 64 + ty*4] = make_uint2(p0, p1);
    }

    if (tid < 64) {
        float s = 0.f;
        #pragma unroll 8
        for (int i = 0; i < 64; ++i) s += Ks[i][tid];
        CKS[(size_t)blockIdx.x * 64 + tid] = s;
    }
}

// ---------------- exclusive prefix over chunks (CKV bf16 in-place + CKS fused) ----------------
__global__ __launch_bounds__(256) void k_prefix(u16* __restrict__ CKV, float* __restrict__ CKS)
{
    if (blockIdx.x < 512) {
        const int bh = blockIdx.x >> 4;
        const int p  = ((blockIdx.x & 15) << 8) + threadIdx.x;
        const size_t base = (size_t)bh * 64 * 4096 + p;
        float acc = 0.f;
        #pragma unroll
        for (int c = 0; c < 64; ++c) {
            float t = bf2f(CKV[base + (size_t)c * 4096]);
            CKV[base + (size_t)c * 4096] = f2bf(acc);
            acc += t;
        }
    } else {
        const int idx = (blockIdx.x - 512) * 256 + threadIdx.x;  // 0..2047
        const int bh = idx >> 6, d = idx & 63;
        const size_t base = (size_t)bh * 64 * 64 + d;
        float v[64];
        #pragma unroll
        for (int c = 0; c < 64; ++c) v[c] = CKS[base + (size_t)c * 64];
        float acc = 0.f;
        #pragma unroll
        for (int c = 0; c < 64; ++c) { float t = v[c]; CKS[base + (size_t)c * 64] = acc; acc += t; }
    }
}

// ---------------- MFMA per-chunk attention ----------------
#define LSTR 72
__global__ __launch_bounds__(256) void k_attn2(
    const u16* __restrict__ Qg, const u16* __restrict__ Kg, const u16* __restrict__ Vg,
    const u16* __restrict__ Stg, const float* __restrict__ KSg, u16* __restrict__ AO)
{
    const int tid = threadIdx.x;
    const int l = tid & 63;
    const int w = tid >> 6;
    const int c  = blockIdx.x & 63;
    const int bh = blockIdx.x >> 6;
    const int row0 = (bh >> 4) * 4096 + c * 64;
    const int col  = (bh & 15) * 64;

    __shared__ __align__(16) u16 Qs [64 * LSTR];
    __shared__ __align__(16) u16 Ks [64 * LSTR];
    __shared__ __align__(16) u16 Vt [64 * LSTR];
    __shared__ __align__(16) u16 Sts[64 * LSTR];
    __shared__ __align__(16) u16 Pl [64 * LSTR];
    __shared__ float ksumF[64];
    __shared__ float invdenL[64];

    #pragma unroll
    for (int r = 0; r < 2; ++r) {
        int idx = tid + r * 256;
        int i = idx >> 3, cg = (idx & 7) << 3;
        *(uint4*)&Qs [i*LSTR + cg] = *(const uint4*)&Qg [(size_t)(row0 + i) * 1024 + col + cg];
        *(uint4*)&Ks [i*LSTR + cg] = *(const uint4*)&Kg [(size_t)(row0 + i) * 1024 + col + cg];
        *(uint4*)&Sts[i*LSTR + cg] = *(const uint4*)&Stg[(size_t)blockIdx.x * 4096 + i * 64 + cg];
        uint4 vu = *(const uint4*)&Vg[(size_t)(row0 + i) * 1024 + col + cg];
        Vt[(cg+0)*LSTR + i] = (u16)(vu.x & 0xffff);
        Vt[(cg+1)*LSTR + i] = (u16)(vu.x >> 16);
        Vt[(cg+2)*LSTR + i] = (u16)(vu.y & 0xffff);
        Vt[(cg+3)*LSTR + i] = (u16)(vu.y >> 16);
        Vt[(cg+4)*LSTR + i] = (u16)(vu.z & 0xffff);
        Vt[(cg+5)*LSTR + i] = (u16)(vu.z >> 16);
        Vt[(cg+6)*LSTR + i] = (u16)(vu.w & 0xffff);
        Vt[(cg+7)*LSTR + i] = (u16)(vu.w >> 16);
    }
    if (tid < 64) ksumF[tid] = KSg[(size_t)blockIdx.x * 64 + tid];
    __syncthreads();

    const int li = l & 15;
    const int lg = l >> 4;
    const int i_row = w * 16 + li;

    short8v bq[2];
    #pragma unroll
    for (int kc = 0; kc < 2; ++kc)
        bq[kc] = *(const short8v*)&Qs[i_row * LSTR + lg*8 + kc*32];

    float den = EPSF;
    #pragma unroll
    for (int mj = 0; mj < 4; ++mj) {
        f32x4 sacc = (f32x4){0.f, 0.f, 0.f, 0.f};
        #pragma unroll
        for (int kc = 0; kc < 2; ++kc) {
            short8v ak = *(const short8v*)&Ks[(mj*16 + li) * LSTR + lg*8 + kc*32];
            sacc = __builtin_amdgcn_mfma_f32_16x16x32_bf16(ak, bq[kc], sacc, 0, 0, 0);
        }
        const int jbase = mj*16 + lg*4;
        float pv[4];
        #pragma unroll
        for (int r = 0; r < 4; ++r) {
            float v = sacc[r];
            v = (jbase + r <= i_row) ? v : 0.f;
            den += v;
            pv[r] = v;
        }
        u32 lo = (u32)f2bf(pv[0]) | ((u32)f2bf(pv[1]) << 16);
        u32 hi = (u32)f2bf(pv[2]) | ((u32)f2bf(pv[3]) << 16);
        *(uint2*)&Pl[i_row * LSTR + jbase] = make_uint2(lo, hi);
    }

    {
        const int d0 = lg * 16;
        uint4 q1 = *(const uint4*)&Qs[i_row * LSTR + d0];
        uint4 q2 = *(const uint4*)&Qs[i_row * LSTR + d0 + 8];
        den += bflo(q1.x)*ksumF[d0+0] + bfhi(q1.x)*ksumF[d0+1]
             + bflo(q1.y)*ksumF[d0+2] + bfhi(q1.y)*ksumF[d0+3]
             + bflo(q1.z)*ksumF[d0+4] + bfhi(q1.z)*ksumF[d0+5]
             + bflo(q1.w)*ksumF[d0+6] + bfhi(q1.w)*ksumF[d0+7]
             + bflo(q2.x)*ksumF[d0+8] + bfhi(q2.x)*ksumF[d0+9]
             + bflo(q2.y)*ksumF[d0+10]+ bfhi(q2.y)*ksumF[d0+11]
             + bflo(q2.z)*ksumF[d0+12]+ bfhi(q2.z)*ksumF[d0+13]
             + bflo(q2.w)*ksumF[d0+14]+ bfhi(q2.w)*ksumF[d0+15];
    }
    den += __shfl_xor(den, 16);
    den += __shfl_xor(den, 32);
    if (l < 16) invdenL[w*16 + l] = 1.f / den;

    f32x4 oacc[4];
    #pragma unroll
    for (int ne = 0; ne < 4; ++ne) oacc[ne] = (f32x4){0.f, 0.f, 0.f, 0.f};
    #pragma unroll
    for (int kc = 0; kc < 2; ++kc) {
        short8v ap = *(const short8v*)&Pl[i_row * LSTR + lg*8 + kc*32];
        short8v aq = bq[kc];
        #pragma unroll
        for (int ne = 0; ne < 4; ++ne) {
            short8v bv = *(const short8v*)&Vt [(ne*16 + li) * LSTR + lg*8 + kc*32];
            short8v bs = *(const short8v*)&Sts[(ne*16 + li) * LSTR + lg*8 + kc*32];
            oacc[ne] = __builtin_amdgcn_mfma_f32_16x16x32_bf16(ap, bv, oacc[ne], 0, 0, 0);
            oacc[ne] = __builtin_amdgcn_mfma_f32_16x16x32_bf16(aq, bs, oacc[ne], 0, 0, 0);
        }
    }

    float inv[4];
    #pragma unroll
    for (int r = 0; r < 4; ++r) inv[r] = invdenL[w*16 + lg*4 + r];
    #pragma unroll
    for (int ne = 0; ne < 4; ++ne)
        #pragma unroll
        for (int r = 0; r < 4; ++r)
            Pl[(w*16 + lg*4 + r) * LSTR + ne*16 + li] = f2bf(oacc[ne][r] * inv[r]);

    #pragma unroll
    for (int p = 0; p < 2; ++p) {
        int idx2 = l + p * 64;
        int ro = w*16 + (idx2 >> 3), cg = (idx2 & 7) << 3;
        *(uint4*)&AO[(size_t)(row0 + ro) * 1024 + col + cg] = *(const uint4*)&Pl[ro*LSTR + cg];
    }
}

extern "C" void kernel_launch(void* const* d_in, const int* in_sizes, int n_in,
                              void* d_out, int out_size, void* d_ws, size_t ws_size,
                              hipStream_t stream)
{
    const float* x  = (const float*)d_in[0];
    const float* Wq = (const float*)d_in[1];
    const float* Wk = (const float*)d_in[2];
    const float* Wv = (const float*)d_in[3];
    const float* Wo = (const float*)d_in[4];
    float* out = (float*)d_out;

    char* w = (char*)d_ws;
    u16*   QKVb = (u16*)(w);                        // 3 x 16777216 B = 50331648
    u16*   Qb   = QKVb;
    u16*   Kb   = QKVb + 8388608;
    u16*   Vb   = QKVb + 16777216;
    u16*   xb   = (u16*)(w + 50331648);             // 16777216 B (aliased AOb)
    u16*   AOb  = xb;
    u16*   Wcat = (u16*)(w + 67108864);             //  6291456 B
    u16*   Wob  = (u16*)(w + 73400320);             //  2097152 B
    u16*   CKVb = (u16*)(w + 75497472);             // 16777216 B (bf16, prefix in-place)
    float* CKS  = (float*)(w + 92274688);           //   524288 B -> end 92798976

    k_cast5       <<<6144, 256, 0, stream>>>(x, Wq, Wk, Wv, Wo, xb, Wcat, Wob);
    k_gemm7<1,24> <<<768,  256, 0, stream>>>(xb, Wcat, (void*)QKVb);
    k_chunksums   <<<2048, 256, 0, stream>>>(Kb, Vb, CKVb, CKS);
    k_prefix      <<<520,  256, 0, stream>>>(CKVb, CKS);
    k_attn2       <<<2048, 256, 0, stream>>>(Qb, Kb, Vb, CKVb, CKS, AOb);
    k_gemm7<3,8>  <<<256,  256, 0, stream>>>(AOb, Wob, (void*)out);
}